// Round 17
// baseline (187.904 us; speedup 1.0000x reference)
//
#include <hip/hip_runtime.h>
#include <hip/hip_bf16.h>
#include <hip/hip_fp16.h>

// ---------------------------------------------------------------------------
// GCN 2-layer inference:
//   h1 = relu( D^-1/2 (A+I) D^-1/2 (x @ W1) + b1 )
//   out = softmax( D^-1/2 (A+I) D^-1/2 (h1 @ W2) + b2 )
//
// memset(bcur) -> bin (packed u32 pairs, LDS counting-sort) -> countfill_b
// (fused hist+prefix+row_ptr/dinv+CSR place) -> prepW -> gemm1_mfma
// (global_load_lds, 3-buffer depth-2 pipeline, counted vmcnt(4) + raw
// s_barrier -- no full drain in main loop) -> agg1 (fp16 gather -> fp16 Y)
// -> gemm2 -> agg2 (+softmax).
//
// Round-16 lesson: gemm1 was ~3x above its stream floor because
// __syncthreads' implicit vmcnt(0) drains the just-issued stage (HBM X
// ~600-900cy). T3/T4: stage 2 ahead, wait vmcnt(4) (previous stage only),
// raw s_barrier -- newest 4 loads stay in flight across the barrier.
// ---------------------------------------------------------------------------

#define F_IN 512
#define NHID 128
#define NCLS 64
#define BSHIFT 8           // 256 nodes per bucket
#define CHUNK 4096         // edges per bin block
#define BM 64
#define BK 32

typedef __attribute__((ext_vector_type(8))) short short8;
typedef __attribute__((ext_vector_type(4))) float f32x4;

__device__ __forceinline__ unsigned f2u(float f) { union { float f; unsigned u; } v; v.f = f; return v.u; }
__device__ __forceinline__ float u2f(unsigned u) { union { unsigned u; float f; } v; v.u = u; return v.f; }

// ---------------- binning: LDS counting-sort, packed u32 pairs ----------------

__global__ __launch_bounds__(256) void bin_kernel(const int* __restrict__ src,
        const int* __restrict__ dst, unsigned* __restrict__ pairs,
        int* __restrict__ bcur, int E, int cap) {
    __shared__ int lcnt[256];
    __shared__ int lscan[256];
    __shared__ int gbase[256];
    __shared__ int wsum[4];
    __shared__ unsigned stage[CHUNK];   // 16KB
    const int t = threadIdx.x;
    const int lane = t & 63, wid = t >> 6;
    const int e0 = blockIdx.x * CHUNK;
    const int n = min(CHUNK, E - e0);

    lcnt[t] = 0;
    __syncthreads();
    for (int i = t; i < n; i += 256)
        atomicAdd(&lcnt[dst[e0 + i] >> BSHIFT], 1);
    __syncthreads();
    const int v = lcnt[t];
    int s = v;
    #pragma unroll
    for (int d = 1; d < 64; d <<= 1) {
        int tt = __shfl_up(s, d);
        if (lane >= d) s += tt;
    }
    if (lane == 63) wsum[wid] = s;
    __syncthreads();
    int woff = 0;
    for (int w = 0; w < wid; ++w) woff += wsum[w];
    lscan[t] = woff + s - v;
    gbase[t] = v ? atomicAdd(&bcur[t], v) : 0;
    lcnt[t] = 0;
    __syncthreads();
    for (int i = t; i < n; i += 256) {
        unsigned d = (unsigned)dst[e0 + i], sc = (unsigned)src[e0 + i];
        int b = d >> BSHIFT;
        int p = atomicAdd(&lcnt[b], 1);
        stage[lscan[b] + p] = (d << 16) | sc;
    }
    __syncthreads();
    for (int i = t; i < n; i += 256) {
        unsigned pr = stage[i];
        int b = pr >> 24;
        int off = gbase[b] + (i - lscan[b]);
        if (off < cap) pairs[(size_t)b * cap + off] = pr;
    }
}

// ---------------- fused: per-bucket hist + prefix -> row_ptr/dinv + CSR place ----------------

__global__ __launch_bounds__(1024) void countfill_b_kernel(
        const unsigned* __restrict__ pairs, const int* __restrict__ bcur,
        int* __restrict__ row_ptr, float* __restrict__ dinv,
        int* __restrict__ col, int cap, int N) {
    __shared__ int hist[256];
    __shared__ int lscan[256];
    __shared__ int red[16];
    __shared__ int wsum[4];
    const int b = blockIdx.x;
    const int t = threadIdx.x;
    const int lane = t & 63, wv = t >> 6;

    int bv = (t < 256 && t < b) ? min(bcur[t], cap) : 0;
    #pragma unroll
    for (int d = 32; d >= 1; d >>= 1) bv += __shfl_xor(bv, d);
    if (lane == 0) red[wv] = bv;
    if (t < 256) hist[t] = 0;
    __syncthreads();
    int bbase = 0;
    #pragma unroll
    for (int w = 0; w < 16; ++w) bbase += red[w];

    const int n = min(bcur[b], cap);
    const unsigned* p = pairs + (size_t)b * cap;
    for (int i = t; i < n; i += 1024)
        atomicAdd(&hist[(p[i] >> 16) & 255], 1);
    __syncthreads();

    int s = 0, v2 = 0;
    if (t < 256) {
        v2 = hist[t];
        s = v2;
        #pragma unroll
        for (int d = 1; d < 64; d <<= 1) {
            int tt = __shfl_up(s, d);
            if (lane >= d) s += tt;
        }
        if (lane == 63) wsum[wv] = s;
    }
    __syncthreads();
    if (t < 256) {
        int woff = 0;
        for (int w = 0; w < wv; ++w) woff += wsum[w];
        const int excl = woff + s - v2;
        lscan[t] = excl;
        const int node = (b << BSHIFT) + t;
        if (node <= N) row_ptr[node] = bbase + excl;
        if (node < N) dinv[node] = rsqrtf((float)v2 + 1.0f);
    }
    __syncthreads();
    if (t < 256) hist[t] = 0;   // reuse as cursor
    __syncthreads();
    for (int i = t; i < n; i += 1024) {
        unsigned pr = p[i];
        int dl = (pr >> 16) & 255;
        int pos = bbase + lscan[dl] + atomicAdd(&hist[dl], 1);
        col[pos] = (int)(pr & 0xffffu);
    }
}

// ---------------- prepW: W1 -> fragment-packed RNE bf16 ----------------

__global__ __launch_bounds__(256) void prepW_kernel(const float* __restrict__ W1,
        short* __restrict__ Wp) {
    const int g = blockIdx.x * 256 + threadIdx.x;  // 0..8191
    const int f = g >> 6;
    const int lane = g & 63;
    const int ks = f >> 3, nt = f & 7;
    const int colg = nt * 16 + (lane & 15);
    const int k0 = ks * 32 + (lane >> 4) * 8;
    short8 vb;
    #pragma unroll
    for (int j = 0; j < 8; ++j) {
        unsigned u = f2u(W1[(size_t)(k0 + j) * NHID + colg]);
        unsigned r = (u + 0x7fffu + ((u >> 16) & 1u)) >> 16;   // RNE
        vb[j] = (short)r;
    }
    *reinterpret_cast<short8*>(Wp + ((size_t)f << 9) + (lane << 3)) = vb;
}

// ---------------- GEMM1: 3-buffer depth-2 pipeline, counted vmcnt ----------------
// 64x128 tile, 4 waves; wave w: rows w*16..+16, all 8 ntiles.
// A tile fp32, source-swizzled (G21); B frag-packed linear.
// iter ks: STAGE(ks+2) -> compute buf[ks%3] -> vmcnt(4) [prev stage only,
// newest 4 stay in flight] -> raw s_barrier. Generation argument:
// barrier(ks) ensures stage(ks+1) landed for all waves; stage(ks+3) is
// issued only after barrier(ks), so no write-after-read on buf[ks%3].

__device__ __forceinline__ void cvt8v(const f32x4& u0, const f32x4& u1,
                                      short8& h, short8& l) {
    float av[8] = {u0[0], u0[1], u0[2], u0[3], u1[0], u1[1], u1[2], u1[3]};
    #pragma unroll
    for (int j = 0; j < 8; ++j) {
        unsigned u = f2u(av[j]);
        h[j] = (short)(u >> 16);
        float hif = u2f(u & 0xffff0000u);
        l[j] = (short)(f2u(av[j] - hif) >> 16);
    }
}

#define STAGE(bufidx, ksv) do { \
    const char* _xb = (const char*)X + (size_t)(ksv) * 128; \
    char* _ab = (char*)&Abuf[bufidx][0] + tid * 16; \
    __builtin_amdgcn_global_load_lds((const unsigned*)(_xb + aoff0), (unsigned*)(_ab),        16, 0, 0); \
    __builtin_amdgcn_global_load_lds((const unsigned*)(_xb + aoff1), (unsigned*)(_ab + 4096), 16, 0, 0); \
    const char* _wb = (const char*)Wp + (size_t)(ksv) * 8192 + tid * 16; \
    char* _bb = (char*)&Bbuf[bufidx][0] + tid * 16; \
    __builtin_amdgcn_global_load_lds((const unsigned*)(_wb),        (unsigned*)(_bb),        16, 0, 0); \
    __builtin_amdgcn_global_load_lds((const unsigned*)(_wb + 4096), (unsigned*)(_bb + 4096), 16, 0, 0); \
} while (0)

__global__ __launch_bounds__(256, 3) void gemm1_mfma(
        const float* __restrict__ X, const short* __restrict__ Wp,
        const float* __restrict__ dinv, __half* __restrict__ Hs16, int M) {
    __shared__ float Abuf[3][BM * BK];   // 8KB each
    __shared__ short Bbuf[3][8 * 512];   // 8KB each
    const int tid = threadIdx.x;
    const int lane = tid & 63;
    const int wid = tid >> 6;
    const int l15 = lane & 15;
    const int kc = lane >> 4;
    const int m0 = blockIdx.x * BM;

    int aoff0, aoff1;
    {
        int o, row, c, grow;
        o = tid * 16;        row = o >> 7; c = ((o >> 4) & 7) ^ (row & 7);
        grow = m0 + row; if (grow > M - 1) grow = M - 1; aoff0 = grow * 2048 + c * 16;
        o = 4096 + tid * 16; row = o >> 7; c = ((o >> 4) & 7) ^ (row & 7);
        grow = m0 + row; if (grow > M - 1) grow = M - 1; aoff1 = grow * 2048 + c * 16;
    }

    const int row0 = wid * 16 + l15;
    const int ra0 = row0 * 128 + (((kc * 2) ^ (row0 & 7)) * 16);
    const int ra1 = row0 * 128 + (((kc * 2 + 1) ^ (row0 & 7)) * 16);

    f32x4 acc[8];
    #pragma unroll
    for (int j = 0; j < 8; ++j)
        acc[j] = (f32x4){0.f, 0.f, 0.f, 0.f};

    // prologue: stage tiles 0 and 1; wait for tile 0 only (vmcnt(4) leaves
    // tile 1's 4 loads in flight), then barrier.
    STAGE(0, 0);
    STAGE(1, 1);
    asm volatile("s_waitcnt vmcnt(4)" ::: "memory");
    __builtin_amdgcn_s_barrier();

    int bs = 0;
    for (int ks = 0; ks < 16; ++ks) {
        if (ks + 2 < 16) {
            int bn = bs + 2; if (bn >= 3) bn -= 3;
            STAGE(bn, ks + 2);
        }
        const char* ab = (const char*)&Abuf[bs][0];
        const f32x4 x0 = *reinterpret_cast<const f32x4*>(ab + ra0);
        const f32x4 x1 = *reinterpret_cast<const f32x4*>(ab + ra1);
        short8 ah, al;
        cvt8v(x0, x1, ah, al);
        const char* bb = (const char*)&Bbuf[bs][0];
        short8 bfr[8];
        #pragma unroll
        for (int nt = 0; nt < 8; ++nt)
            bfr[nt] = *reinterpret_cast<const short8*>(bb + nt * 1024 + lane * 16);
        #pragma unroll
        for (int nt = 0; nt < 8; ++nt) {
            acc[nt] = __builtin_amdgcn_mfma_f32_16x16x32_bf16(ah, bfr[nt], acc[nt], 0, 0, 0);
            acc[nt] = __builtin_amdgcn_mfma_f32_16x16x32_bf16(al, bfr[nt], acc[nt], 0, 0, 0);
        }
        if (ks < 15) {
            if (ks + 2 < 16) {
                asm volatile("s_waitcnt vmcnt(4)" ::: "memory");   // prev stage landed
            } else {
                asm volatile("s_waitcnt vmcnt(0)" ::: "memory");   // tail drain
            }
            __builtin_amdgcn_s_barrier();
        }
        ++bs; if (bs >= 3) bs -= 3;
    }

    #pragma unroll
    for (int r = 0; r < 4; ++r) {
        const int orow = m0 + wid * 16 + kc * 4 + r;
        if (orow < M) {
            const float di = dinv[orow];
            #pragma unroll
            for (int nt = 0; nt < 8; ++nt) {
                Hs16[(size_t)orow * NHID + nt * 16 + l15] =
                    __float2half(acc[nt][r] * di);
            }
        }
    }
}

// ---------------- AGG1: Y16 = fp16(relu(dinv[i]*(Hs[i] + sum Hs[src]) + b1)) ----------------

__global__ __launch_bounds__(64) void agg1_kernel(const __half2* __restrict__ Hs,
        const int* __restrict__ row_ptr, const int* __restrict__ col,
        const float* __restrict__ dinv, const float* __restrict__ b1,
        __half2* __restrict__ Y16) {
    const int i = blockIdx.x;
    const int c = threadIdx.x;           // col-pair 0..63
    const int beg = row_ptr[i], end = row_ptr[i + 1];
    float2 f = __half22float2(Hs[(size_t)i * 64 + c]);
    float ax = f.x, ay = f.y;
    int e = beg;
    for (; e + 8 <= end; e += 8) {
        float2 v[8];
        #pragma unroll
        for (int j = 0; j < 8; ++j) {
            int s = col[e + j];
            v[j] = __half22float2(Hs[(size_t)s * 64 + c]);
        }
        #pragma unroll
        for (int j = 0; j < 8; ++j) { ax += v[j].x; ay += v[j].y; }
    }
    for (; e < end; ++e) {
        float2 v = __half22float2(Hs[(size_t)col[e] * 64 + c]);
        ax += v.x; ay += v.y;
    }
    const float di = dinv[i];
    const float2 bb = reinterpret_cast<const float2*>(b1)[c];
    float ox = fmaxf(fmaf(ax, di, bb.x), 0.0f);
    float oy = fmaxf(fmaf(ay, di, bb.y), 0.0f);
    Y16[(size_t)i * 64 + c] = __floats2half2_rn(ox, oy);
}

// ---------------- GEMM2: H2s16 = fp16((Y16 @ W2) * dinv[row])  [N,64] ----------------

__global__ __launch_bounds__(256) void gemm2_kernel(const __half2* __restrict__ Y16,
        const float* __restrict__ W2, const float* __restrict__ dinv,
        __half* __restrict__ H2s16, int N) {
    __shared__ float Ws[NHID][NCLS];     // 32KB
    __shared__ __half2 Ys2[16][NCLS];    // 4KB
    const int tid = threadIdx.x;
    const int i0 = blockIdx.x * 16;
    #pragma unroll
    for (int t = 0; t < 8; ++t) {
        int v = tid + t * 256;
        int k = v >> 4;
        int c4 = (v & 15) * 4;
        *reinterpret_cast<float4*>(&Ws[k][c4]) =
            *reinterpret_cast<const float4*>(&W2[(size_t)k * NCLS + c4]);
    }
    {
        int r = tid >> 4;
        int c4 = (tid & 15) * 4;
        int gr = i0 + r; if (gr > N - 1) gr = N - 1;
        *reinterpret_cast<float4*>(&Ys2[r][c4]) =
            *reinterpret_cast<const float4*>(&Y16[(size_t)gr * 64 + c4]);
    }
    __syncthreads();
    const int c = tid & 63;
    const int rg = tid >> 6;
    float acc[4] = {0.f, 0.f, 0.f, 0.f};
    #pragma unroll 8
    for (int kp = 0; kp < 64; ++kp) {
        const float w0 = Ws[2 * kp][c];
        const float w1 = Ws[2 * kp + 1][c];
        #pragma unroll
        for (int j = 0; j < 4; ++j) {
            float2 y2 = __half22float2(Ys2[rg * 4 + j][kp]);
            acc[j] = fmaf(y2.x, w0, fmaf(y2.y, w1, acc[j]));
        }
    }
    #pragma unroll
    for (int j = 0; j < 4; ++j) {
        int gr = i0 + rg * 4 + j;
        if (gr < N) H2s16[(size_t)gr * NCLS + c] = __float2half(acc[j] * dinv[gr]);
    }
}

// ---------------- AGG2 + softmax: two nodes per wave ----------------

__global__ __launch_bounds__(64) void agg2_kernel(const __half2* __restrict__ H2,
        const int* __restrict__ row_ptr, const int* __restrict__ col,
        const float* __restrict__ dinv, const float* __restrict__ b2,
        float* __restrict__ out, int N) {
    const int lane = threadIdx.x;
    const int node = blockIdx.x * 2 + (lane >> 5);
    const int c = lane & 31;             // col-pair 0..31
    if (node >= N) return;
    const int beg = row_ptr[node], end = row_ptr[node + 1];
    float2 f = __half22float2(H2[(size_t)node * 32 + c]);
    float ax = f.x, ay = f.y;
    int e = beg;
    for (; e + 8 <= end; e += 8) {
        float2 v[8];
        #pragma unroll
        for (int j = 0; j < 8; ++j) {
            int s = col[e + j];
            v[j] = __half22float2(H2[(size_t)s * 32 + c]);
        }
        #pragma unroll
        for (int j = 0; j < 8; ++j) { ax += v[j].x; ay += v[j].y; }
    }
    for (; e < end; ++e) {
        float2 v = __half22float2(H2[(size_t)col[e] * 32 + c]);
        ax += v.x; ay += v.y;
    }
    const float di = dinv[node];
    const float2 bb = reinterpret_cast<const float2*>(b2)[c];
    float vx = fmaf(ax, di, bb.x);
    float vy = fmaf(ay, di, bb.y);
    float m = fmaxf(vx, vy);
    #pragma unroll
    for (int d = 16; d >= 1; d >>= 1) m = fmaxf(m, __shfl_xor(m, d));
    float ex = __expf(vx - m), ey = __expf(vy - m);
    float sum = ex + ey;
    #pragma unroll
    for (int d = 16; d >= 1; d >>= 1) sum += __shfl_xor(sum, d);
    float2 o = {ex / sum, ey / sum};
    reinterpret_cast<float2*>(out)[(size_t)node * 32 + c] = o;
}

// ---------------- launch ----------------

extern "C" void kernel_launch(void* const* d_in, const int* in_sizes, int n_in,
                              void* d_out, int out_size, void* d_ws, size_t ws_size,
                              hipStream_t stream) {
    const float* x  = (const float*)d_in[0];
    const int*   ei = (const int*)d_in[1];
    const float* W1 = (const float*)d_in[2];
    const float* b1 = (const float*)d_in[3];
    const float* W2 = (const float*)d_in[4];
    const float* b2 = (const float*)d_in[5];
    const int N = in_sizes[0] / F_IN;
    const int E = in_sizes[1] / 2;
    const int* src = ei;
    const int* dst = ei + E;
    float* out = (float*)d_out;

    const int Npad  = (N + 63) & ~63;             // >= N+1
    const int Epad  = (E + 63) & ~63;
    const int nbuck = (N + 255) >> BSHIFT;                  // 196
    const int cap = (((E / nbuck) * 3 / 2) + 63) & ~63;     // ~12288

    int*      bcur    = (int*)d_ws;                           // 256
    int*      row_ptr = bcur + 256;                           // Npad
    float*    dinv    = (float*)(row_ptr + Npad);             // Npad
    int*      col     = (int*)(dinv + Npad);                  // Epad
    __half*   Hs16    = (__half*)(col + Epad);                // Npad*128 (12.8MB)
    __half2*  Y16     = (__half2*)(Hs16 + (size_t)Npad * NHID); // Npad*64 half2 (6.4MB)
    short*    Wp      = (short*)(Y16 + (size_t)Npad * 64);    // 65536 shorts (128KB)
    unsigned* pairs   = (unsigned*)(Wp + 65536);              // nbuck*cap u32 (~9.6MB)
    __half*   H2s16   = Hs16;                                 // reuse (Hs dead after agg1)

    hipMemsetAsync(bcur, 0, 256 * sizeof(int), stream);
    bin_kernel<<<(E + CHUNK - 1) / CHUNK, 256, 0, stream>>>(src, dst, pairs, bcur, E, cap);
    countfill_b_kernel<<<nbuck, 1024, 0, stream>>>(pairs, bcur, row_ptr, dinv, col, cap, N);
    prepW_kernel<<<32, 256, 0, stream>>>(W1, Wp);
    gemm1_mfma<<<(N + BM - 1) / BM, 256, 0, stream>>>(x, Wp, dinv, Hs16, N);
    agg1_kernel<<<N, 64, 0, stream>>>((const __half2*)Hs16, row_ptr, col, dinv, b1, Y16);
    gemm2_kernel<<<(N + 15) / 16, 256, 0, stream>>>(Y16, W2, dinv, H2s16, N);
    agg2_kernel<<<(N + 1) / 2, 64, 0, stream>>>((const __half2*)H2s16, row_ptr, col, dinv, b2, out, N);
}

// Round 18
// 177.459 us; speedup vs baseline: 1.0589x; 1.0589x over previous
//
#include <hip/hip_runtime.h>
#include <hip/hip_bf16.h>
#include <hip/hip_fp16.h>

// ---------------------------------------------------------------------------
// GCN 2-layer inference:
//   h1 = relu( D^-1/2 (A+I) D^-1/2 (x @ W1) + b1 )
//   out = softmax( D^-1/2 (A+I) D^-1/2 (h1 @ W2) + b2 )
//
// memset(bcur) -> bin (packed u32 pairs, LDS counting-sort) -> countfill_b
// (fused hist+prefix+row_ptr/dinv+CSR place) -> prepW -> gemm1_mfma
// (m97-style global_load_lds, 2-buffer, __syncthreads, 4 blocks/CU -- the
// R16 empirical optimum; counted-vmcnt variants all regressed) -> agg1
// (fp16 gather, 4 nodes/block) -> gemm2 -> agg2 (8 nodes/block, +softmax).
//
// Round-17 lesson: 3-buffer counted-vmcnt dropped gemm1 to 3 blocks/CU and
// LOST 15us -- cross-block TLP (4 blocks/CU) was what hid the drain, not
// intra-wave pipelining. gemm1 scheduling closed at the R16 structure.
// ---------------------------------------------------------------------------

#define F_IN 512
#define NHID 128
#define NCLS 64
#define BSHIFT 8           // 256 nodes per bucket
#define CHUNK 4096         // edges per bin block
#define BM 64
#define BK 32

typedef __attribute__((ext_vector_type(8))) short short8;
typedef __attribute__((ext_vector_type(4))) float f32x4;

__device__ __forceinline__ unsigned f2u(float f) { union { float f; unsigned u; } v; v.f = f; return v.u; }
__device__ __forceinline__ float u2f(unsigned u) { union { unsigned u; float f; } v; v.u = u; return v.f; }

// ---------------- binning: LDS counting-sort, packed u32 pairs ----------------

__global__ __launch_bounds__(256) void bin_kernel(const int* __restrict__ src,
        const int* __restrict__ dst, unsigned* __restrict__ pairs,
        int* __restrict__ bcur, int E, int cap) {
    __shared__ int lcnt[256];
    __shared__ int lscan[256];
    __shared__ int gbase[256];
    __shared__ int wsum[4];
    __shared__ unsigned stage[CHUNK];   // 16KB
    const int t = threadIdx.x;
    const int lane = t & 63, wid = t >> 6;
    const int e0 = blockIdx.x * CHUNK;
    const int n = min(CHUNK, E - e0);

    lcnt[t] = 0;
    __syncthreads();
    for (int i = t; i < n; i += 256)
        atomicAdd(&lcnt[dst[e0 + i] >> BSHIFT], 1);
    __syncthreads();
    const int v = lcnt[t];
    int s = v;
    #pragma unroll
    for (int d = 1; d < 64; d <<= 1) {
        int tt = __shfl_up(s, d);
        if (lane >= d) s += tt;
    }
    if (lane == 63) wsum[wid] = s;
    __syncthreads();
    int woff = 0;
    for (int w = 0; w < wid; ++w) woff += wsum[w];
    lscan[t] = woff + s - v;
    gbase[t] = v ? atomicAdd(&bcur[t], v) : 0;
    lcnt[t] = 0;
    __syncthreads();
    for (int i = t; i < n; i += 256) {
        unsigned d = (unsigned)dst[e0 + i], sc = (unsigned)src[e0 + i];
        int b = d >> BSHIFT;
        int p = atomicAdd(&lcnt[b], 1);
        stage[lscan[b] + p] = (d << 16) | sc;
    }
    __syncthreads();
    for (int i = t; i < n; i += 256) {
        unsigned pr = stage[i];
        int b = pr >> 24;
        int off = gbase[b] + (i - lscan[b]);
        if (off < cap) pairs[(size_t)b * cap + off] = pr;
    }
}

// ---------------- fused: per-bucket hist + prefix -> row_ptr/dinv + CSR place ----------------

__global__ __launch_bounds__(1024) void countfill_b_kernel(
        const unsigned* __restrict__ pairs, const int* __restrict__ bcur,
        int* __restrict__ row_ptr, float* __restrict__ dinv,
        int* __restrict__ col, int cap, int N) {
    __shared__ int hist[256];
    __shared__ int lscan[256];
    __shared__ int red[16];
    __shared__ int wsum[4];
    const int b = blockIdx.x;
    const int t = threadIdx.x;
    const int lane = t & 63, wv = t >> 6;

    int bv = (t < 256 && t < b) ? min(bcur[t], cap) : 0;
    #pragma unroll
    for (int d = 32; d >= 1; d >>= 1) bv += __shfl_xor(bv, d);
    if (lane == 0) red[wv] = bv;
    if (t < 256) hist[t] = 0;
    __syncthreads();
    int bbase = 0;
    #pragma unroll
    for (int w = 0; w < 16; ++w) bbase += red[w];

    const int n = min(bcur[b], cap);
    const unsigned* p = pairs + (size_t)b * cap;
    for (int i = t; i < n; i += 1024)
        atomicAdd(&hist[(p[i] >> 16) & 255], 1);
    __syncthreads();

    int s = 0, v2 = 0;
    if (t < 256) {
        v2 = hist[t];
        s = v2;
        #pragma unroll
        for (int d = 1; d < 64; d <<= 1) {
            int tt = __shfl_up(s, d);
            if (lane >= d) s += tt;
        }
        if (lane == 63) wsum[wv] = s;
    }
    __syncthreads();
    if (t < 256) {
        int woff = 0;
        for (int w = 0; w < wv; ++w) woff += wsum[w];
        const int excl = woff + s - v2;
        lscan[t] = excl;
        const int node = (b << BSHIFT) + t;
        if (node <= N) row_ptr[node] = bbase + excl;
        if (node < N) dinv[node] = rsqrtf((float)v2 + 1.0f);
    }
    __syncthreads();
    if (t < 256) hist[t] = 0;   // reuse as cursor
    __syncthreads();
    for (int i = t; i < n; i += 1024) {
        unsigned pr = p[i];
        int dl = (pr >> 16) & 255;
        int pos = bbase + lscan[dl] + atomicAdd(&hist[dl], 1);
        col[pos] = (int)(pr & 0xffffu);
    }
}

// ---------------- prepW: W1 -> fragment-packed RNE bf16 ----------------

__global__ __launch_bounds__(256) void prepW_kernel(const float* __restrict__ W1,
        short* __restrict__ Wp) {
    const int g = blockIdx.x * 256 + threadIdx.x;  // 0..8191
    const int f = g >> 6;
    const int lane = g & 63;
    const int ks = f >> 3, nt = f & 7;
    const int colg = nt * 16 + (lane & 15);
    const int k0 = ks * 32 + (lane >> 4) * 8;
    short8 vb;
    #pragma unroll
    for (int j = 0; j < 8; ++j) {
        unsigned u = f2u(W1[(size_t)(k0 + j) * NHID + colg]);
        unsigned r = (u + 0x7fffu + ((u >> 16) & 1u)) >> 16;   // RNE
        vb[j] = (short)r;
    }
    *reinterpret_cast<short8*>(Wp + ((size_t)f << 9) + (lane << 3)) = vb;
}

// ---------------- GEMM1: m97-style global_load_lds + MFMA, BM=64 (R16) ----------------

__device__ __forceinline__ void cvt8v(const f32x4& u0, const f32x4& u1,
                                      short8& h, short8& l) {
    float av[8] = {u0[0], u0[1], u0[2], u0[3], u1[0], u1[1], u1[2], u1[3]};
    #pragma unroll
    for (int j = 0; j < 8; ++j) {
        unsigned u = f2u(av[j]);
        h[j] = (short)(u >> 16);
        float hif = u2f(u & 0xffff0000u);
        l[j] = (short)(f2u(av[j] - hif) >> 16);
    }
}

#define STAGE(bufidx, ksv) do { \
    const char* _xb = (const char*)X + (size_t)(ksv) * 128; \
    char* _ab = (char*)&Abuf[bufidx][0] + tid * 16; \
    __builtin_amdgcn_global_load_lds((const unsigned*)(_xb + aoff0), (unsigned*)(_ab),        16, 0, 0); \
    __builtin_amdgcn_global_load_lds((const unsigned*)(_xb + aoff1), (unsigned*)(_ab + 4096), 16, 0, 0); \
    const char* _wb = (const char*)Wp + (size_t)(ksv) * 8192 + tid * 16; \
    char* _bb = (char*)&Bbuf[bufidx][0] + tid * 16; \
    __builtin_amdgcn_global_load_lds((const unsigned*)(_wb),        (unsigned*)(_bb),        16, 0, 0); \
    __builtin_amdgcn_global_load_lds((const unsigned*)(_wb + 4096), (unsigned*)(_bb + 4096), 16, 0, 0); \
} while (0)

__global__ __launch_bounds__(256, 4) void gemm1_mfma(
        const float* __restrict__ X, const short* __restrict__ Wp,
        const float* __restrict__ dinv, __half* __restrict__ Hs16, int M) {
    __shared__ float Abuf[2][BM * BK];   // 8KB each
    __shared__ short Bbuf[2][8 * 512];   // 8KB each
    const int tid = threadIdx.x;
    const int lane = tid & 63;
    const int wid = tid >> 6;
    const int l15 = lane & 15;
    const int kc = lane >> 4;
    const int m0 = blockIdx.x * BM;

    int aoff0, aoff1;
    {
        int o, row, c, grow;
        o = tid * 16;        row = o >> 7; c = ((o >> 4) & 7) ^ (row & 7);
        grow = m0 + row; if (grow > M - 1) grow = M - 1; aoff0 = grow * 2048 + c * 16;
        o = 4096 + tid * 16; row = o >> 7; c = ((o >> 4) & 7) ^ (row & 7);
        grow = m0 + row; if (grow > M - 1) grow = M - 1; aoff1 = grow * 2048 + c * 16;
    }

    const int row0 = wid * 16 + l15;
    const int ra0 = row0 * 128 + (((kc * 2) ^ (row0 & 7)) * 16);
    const int ra1 = row0 * 128 + (((kc * 2 + 1) ^ (row0 & 7)) * 16);

    f32x4 acc[8];
    #pragma unroll
    for (int j = 0; j < 8; ++j)
        acc[j] = (f32x4){0.f, 0.f, 0.f, 0.f};

    STAGE(0, 0);
    __syncthreads();

    for (int ks = 0; ks < 16; ++ks) {
        const int cur = ks & 1;
        if (ks + 1 < 16) STAGE(cur ^ 1, ks + 1);
        const char* ab = (const char*)&Abuf[cur][0];
        const f32x4 x0 = *reinterpret_cast<const f32x4*>(ab + ra0);
        const f32x4 x1 = *reinterpret_cast<const f32x4*>(ab + ra1);
        short8 ah, al;
        cvt8v(x0, x1, ah, al);
        const char* bb = (const char*)&Bbuf[cur][0];
        short8 bfr[8];
        #pragma unroll
        for (int nt = 0; nt < 8; ++nt)
            bfr[nt] = *reinterpret_cast<const short8*>(bb + nt * 1024 + lane * 16);
        #pragma unroll
        for (int nt = 0; nt < 8; ++nt) {
            acc[nt] = __builtin_amdgcn_mfma_f32_16x16x32_bf16(ah, bfr[nt], acc[nt], 0, 0, 0);
            acc[nt] = __builtin_amdgcn_mfma_f32_16x16x32_bf16(al, bfr[nt], acc[nt], 0, 0, 0);
        }
        __syncthreads();
    }

    #pragma unroll
    for (int r = 0; r < 4; ++r) {
        const int orow = m0 + wid * 16 + kc * 4 + r;
        if (orow < M) {
            const float di = dinv[orow];
            #pragma unroll
            for (int nt = 0; nt < 8; ++nt) {
                Hs16[(size_t)orow * NHID + nt * 16 + l15] =
                    __float2half(acc[nt][r] * di);
            }
        }
    }
}

// ---------------- AGG1: 4 nodes/block; Y16 = fp16(relu(dinv*(self+sum)+b1)) ----------------

__global__ __launch_bounds__(256) void agg1_kernel(const __half2* __restrict__ Hs,
        const int* __restrict__ row_ptr, const int* __restrict__ col,
        const float* __restrict__ dinv, const float* __restrict__ b1,
        __half2* __restrict__ Y16, int N) {
    const int i = blockIdx.x * 4 + (threadIdx.x >> 6);
    const int c = threadIdx.x & 63;      // col-pair 0..63
    if (i >= N) return;
    const int beg = row_ptr[i], end = row_ptr[i + 1];
    float2 f = __half22float2(Hs[(size_t)i * 64 + c]);
    float ax = f.x, ay = f.y;
    int e = beg;
    for (; e + 8 <= end; e += 8) {
        float2 v[8];
        #pragma unroll
        for (int j = 0; j < 8; ++j) {
            int s = col[e + j];
            v[j] = __half22float2(Hs[(size_t)s * 64 + c]);
        }
        #pragma unroll
        for (int j = 0; j < 8; ++j) { ax += v[j].x; ay += v[j].y; }
    }
    for (; e < end; ++e) {
        float2 v = __half22float2(Hs[(size_t)col[e] * 64 + c]);
        ax += v.x; ay += v.y;
    }
    const float di = dinv[i];
    const float2 bb = reinterpret_cast<const float2*>(b1)[c];
    float ox = fmaxf(fmaf(ax, di, bb.x), 0.0f);
    float oy = fmaxf(fmaf(ay, di, bb.y), 0.0f);
    Y16[(size_t)i * 64 + c] = __floats2half2_rn(ox, oy);
}

// ---------------- GEMM2: H2s16 = fp16((Y16 @ W2) * dinv[row])  [N,64] ----------------

__global__ __launch_bounds__(256) void gemm2_kernel(const __half2* __restrict__ Y16,
        const float* __restrict__ W2, const float* __restrict__ dinv,
        __half* __restrict__ H2s16, int N) {
    __shared__ float Ws[NHID][NCLS];     // 32KB
    __shared__ __half2 Ys2[16][NCLS];    // 4KB
    const int tid = threadIdx.x;
    const int i0 = blockIdx.x * 16;
    #pragma unroll
    for (int t = 0; t < 8; ++t) {
        int v = tid + t * 256;
        int k = v >> 4;
        int c4 = (v & 15) * 4;
        *reinterpret_cast<float4*>(&Ws[k][c4]) =
            *reinterpret_cast<const float4*>(&W2[(size_t)k * NCLS + c4]);
    }
    {
        int r = tid >> 4;
        int c4 = (tid & 15) * 4;
        int gr = i0 + r; if (gr > N - 1) gr = N - 1;
        *reinterpret_cast<float4*>(&Ys2[r][c4]) =
            *reinterpret_cast<const float4*>(&Y16[(size_t)gr * 64 + c4]);
    }
    __syncthreads();
    const int c = tid & 63;
    const int rg = tid >> 6;
    float acc[4] = {0.f, 0.f, 0.f, 0.f};
    #pragma unroll 8
    for (int kp = 0; kp < 64; ++kp) {
        const float w0 = Ws[2 * kp][c];
        const float w1 = Ws[2 * kp + 1][c];
        #pragma unroll
        for (int j = 0; j < 4; ++j) {
            float2 y2 = __half22float2(Ys2[rg * 4 + j][kp]);
            acc[j] = fmaf(y2.x, w0, fmaf(y2.y, w1, acc[j]));
        }
    }
    #pragma unroll
    for (int j = 0; j < 4; ++j) {
        int gr = i0 + rg * 4 + j;
        if (gr < N) H2s16[(size_t)gr * NCLS + c] = __float2half(acc[j] * dinv[gr]);
    }
}

// ---------------- AGG2 + softmax: 8 nodes/block (32 lanes each) ----------------

__global__ __launch_bounds__(256) void agg2_kernel(const __half2* __restrict__ H2,
        const int* __restrict__ row_ptr, const int* __restrict__ col,
        const float* __restrict__ dinv, const float* __restrict__ b2,
        float* __restrict__ out, int N) {
    const int node = blockIdx.x * 8 + (threadIdx.x >> 5);
    const int c = threadIdx.x & 31;      // col-pair 0..31
    if (node >= N) return;
    const int beg = row_ptr[node], end = row_ptr[node + 1];
    float2 f = __half22float2(H2[(size_t)node * 32 + c]);
    float ax = f.x, ay = f.y;
    int e = beg;
    for (; e + 8 <= end; e += 8) {
        float2 v[8];
        #pragma unroll
        for (int j = 0; j < 8; ++j) {
            int s = col[e + j];
            v[j] = __half22float2(H2[(size_t)s * 32 + c]);
        }
        #pragma unroll
        for (int j = 0; j < 8; ++j) { ax += v[j].x; ay += v[j].y; }
    }
    for (; e < end; ++e) {
        float2 v = __half22float2(H2[(size_t)col[e] * 32 + c]);
        ax += v.x; ay += v.y;
    }
    const float di = dinv[node];
    const float2 bb = reinterpret_cast<const float2*>(b2)[c];
    float vx = fmaf(ax, di, bb.x);
    float vy = fmaf(ay, di, bb.y);
    float m = fmaxf(vx, vy);
    #pragma unroll
    for (int d = 16; d >= 1; d >>= 1) m = fmaxf(m, __shfl_xor(m, d));
    float ex = __expf(vx - m), ey = __expf(vy - m);
    float sum = ex + ey;
    #pragma unroll
    for (int d = 16; d >= 1; d >>= 1) sum += __shfl_xor(sum, d);
    float2 o = {ex / sum, ey / sum};
    reinterpret_cast<float2*>(out)[(size_t)node * 32 + c] = o;
}

// ---------------- launch ----------------

extern "C" void kernel_launch(void* const* d_in, const int* in_sizes, int n_in,
                              void* d_out, int out_size, void* d_ws, size_t ws_size,
                              hipStream_t stream) {
    const float* x  = (const float*)d_in[0];
    const int*   ei = (const int*)d_in[1];
    const float* W1 = (const float*)d_in[2];
    const float* b1 = (const float*)d_in[3];
    const float* W2 = (const float*)d_in[4];
    const float* b2 = (const float*)d_in[5];
    const int N = in_sizes[0] / F_IN;
    const int E = in_sizes[1] / 2;
    const int* src = ei;
    const int* dst = ei + E;
    float* out = (float*)d_out;

    const int Npad  = (N + 63) & ~63;             // >= N+1
    const int Epad  = (E + 63) & ~63;
    const int nbuck = (N + 255) >> BSHIFT;                  // 196
    const int cap = (((E / nbuck) * 3 / 2) + 63) & ~63;     // ~12288

    int*      bcur    = (int*)d_ws;                           // 256
    int*      row_ptr = bcur + 256;                           // Npad
    float*    dinv    = (float*)(row_ptr + Npad);             // Npad
    int*      col     = (int*)(dinv + Npad);                  // Epad
    __half*   Hs16    = (__half*)(col + Epad);                // Npad*128 (12.8MB)
    __half2*  Y16     = (__half2*)(Hs16 + (size_t)Npad * NHID); // Npad*64 half2 (6.4MB)
    short*    Wp      = (short*)(Y16 + (size_t)Npad * 64);    // 65536 shorts (128KB)
    unsigned* pairs   = (unsigned*)(Wp + 65536);              // nbuck*cap u32 (~9.6MB)
    __half*   H2s16   = Hs16;                                 // reuse (Hs dead after agg1)

    hipMemsetAsync(bcur, 0, 256 * sizeof(int), stream);
    bin_kernel<<<(E + CHUNK - 1) / CHUNK, 256, 0, stream>>>(src, dst, pairs, bcur, E, cap);
    countfill_b_kernel<<<nbuck, 1024, 0, stream>>>(pairs, bcur, row_ptr, dinv, col, cap, N);
    prepW_kernel<<<32, 256, 0, stream>>>(W1, Wp);
    gemm1_mfma<<<(N + BM - 1) / BM, 256, 0, stream>>>(x, Wp, dinv, Hs16, N);
    agg1_kernel<<<(N + 3) / 4, 256, 0, stream>>>((const __half2*)Hs16, row_ptr, col, dinv, b1, Y16, N);
    gemm2_kernel<<<(N + 15) / 16, 256, 0, stream>>>(Y16, W2, dinv, H2s16, N);
    agg2_kernel<<<(N + 7) / 8, 256, 0, stream>>>((const __half2*)H2s16, row_ptr, col, dinv, b2, out, N);
}

// Round 19
// 171.127 us; speedup vs baseline: 1.0980x; 1.0370x over previous
//
#include <hip/hip_runtime.h>
#include <hip/hip_bf16.h>
#include <hip/hip_fp16.h>

// ---------------------------------------------------------------------------
// GCN 2-layer inference:
//   h1 = relu( D^-1/2 (A+I) D^-1/2 (x @ W1) + b1 )
//   out = softmax( D^-1/2 (A+I) D^-1/2 (h1 @ W2) + b2 )
//
// memset(bcur) -> bin (packed u32 pairs, LDS counting-sort) -> countfill_b
// (fused hist+prefix+row_ptr/dinv+CSR place, ushort col) -> prepW ->
// gemm1_mfma (m97-style global_load_lds, 2-buffer, __syncthreads,
// 4 blocks/CU -- empirical optimum) -> agg1 (fp16 gather, 1 node/block,
// 64 thr) -> gemm2 -> agg2 (2 nodes/wave, +softmax).
//
// Round-18 lesson: multi-node agg blocks couple completion to the max
// degree in the block (+20% agg time). 1-node blocks load-balance free.
// col as ushort: src<2^16, halves col traffic in 3 kernels.
// ---------------------------------------------------------------------------

#define F_IN 512
#define NHID 128
#define NCLS 64
#define BSHIFT 8           // 256 nodes per bucket
#define CHUNK 4096         // edges per bin block
#define BM 64
#define BK 32

typedef __attribute__((ext_vector_type(8))) short short8;
typedef __attribute__((ext_vector_type(4))) float f32x4;

__device__ __forceinline__ unsigned f2u(float f) { union { float f; unsigned u; } v; v.f = f; return v.u; }
__device__ __forceinline__ float u2f(unsigned u) { union { unsigned u; float f; } v; v.u = u; return v.f; }

// ---------------- binning: LDS counting-sort, packed u32 pairs ----------------

__global__ __launch_bounds__(256) void bin_kernel(const int* __restrict__ src,
        const int* __restrict__ dst, unsigned* __restrict__ pairs,
        int* __restrict__ bcur, int E, int cap) {
    __shared__ int lcnt[256];
    __shared__ int lscan[256];
    __shared__ int gbase[256];
    __shared__ int wsum[4];
    __shared__ unsigned stage[CHUNK];   // 16KB
    const int t = threadIdx.x;
    const int lane = t & 63, wid = t >> 6;
    const int e0 = blockIdx.x * CHUNK;
    const int n = min(CHUNK, E - e0);

    lcnt[t] = 0;
    __syncthreads();
    for (int i = t; i < n; i += 256)
        atomicAdd(&lcnt[dst[e0 + i] >> BSHIFT], 1);
    __syncthreads();
    const int v = lcnt[t];
    int s = v;
    #pragma unroll
    for (int d = 1; d < 64; d <<= 1) {
        int tt = __shfl_up(s, d);
        if (lane >= d) s += tt;
    }
    if (lane == 63) wsum[wid] = s;
    __syncthreads();
    int woff = 0;
    for (int w = 0; w < wid; ++w) woff += wsum[w];
    lscan[t] = woff + s - v;
    gbase[t] = v ? atomicAdd(&bcur[t], v) : 0;
    lcnt[t] = 0;
    __syncthreads();
    for (int i = t; i < n; i += 256) {
        unsigned d = (unsigned)dst[e0 + i], sc = (unsigned)src[e0 + i];
        int b = d >> BSHIFT;
        int p = atomicAdd(&lcnt[b], 1);
        stage[lscan[b] + p] = (d << 16) | sc;
    }
    __syncthreads();
    for (int i = t; i < n; i += 256) {
        unsigned pr = stage[i];
        int b = pr >> 24;
        int off = gbase[b] + (i - lscan[b]);
        if (off < cap) pairs[(size_t)b * cap + off] = pr;
    }
}

// ---------------- fused: per-bucket hist + prefix -> row_ptr/dinv + CSR place ----------------

__global__ __launch_bounds__(1024) void countfill_b_kernel(
        const unsigned* __restrict__ pairs, const int* __restrict__ bcur,
        int* __restrict__ row_ptr, float* __restrict__ dinv,
        unsigned short* __restrict__ col, int cap, int N) {
    __shared__ int hist[256];
    __shared__ int lscan[256];
    __shared__ int red[16];
    __shared__ int wsum[4];
    const int b = blockIdx.x;
    const int t = threadIdx.x;
    const int lane = t & 63, wv = t >> 6;

    int bv = (t < 256 && t < b) ? min(bcur[t], cap) : 0;
    #pragma unroll
    for (int d = 32; d >= 1; d >>= 1) bv += __shfl_xor(bv, d);
    if (lane == 0) red[wv] = bv;
    if (t < 256) hist[t] = 0;
    __syncthreads();
    int bbase = 0;
    #pragma unroll
    for (int w = 0; w < 16; ++w) bbase += red[w];

    const int n = min(bcur[b], cap);
    const unsigned* p = pairs + (size_t)b * cap;
    for (int i = t; i < n; i += 1024)
        atomicAdd(&hist[(p[i] >> 16) & 255], 1);
    __syncthreads();

    int s = 0, v2 = 0;
    if (t < 256) {
        v2 = hist[t];
        s = v2;
        #pragma unroll
        for (int d = 1; d < 64; d <<= 1) {
            int tt = __shfl_up(s, d);
            if (lane >= d) s += tt;
        }
        if (lane == 63) wsum[wv] = s;
    }
    __syncthreads();
    if (t < 256) {
        int woff = 0;
        for (int w = 0; w < wv; ++w) woff += wsum[w];
        const int excl = woff + s - v2;
        lscan[t] = excl;
        const int node = (b << BSHIFT) + t;
        if (node <= N) row_ptr[node] = bbase + excl;
        if (node < N) dinv[node] = rsqrtf((float)v2 + 1.0f);
    }
    __syncthreads();
    if (t < 256) hist[t] = 0;   // reuse as cursor
    __syncthreads();
    for (int i = t; i < n; i += 1024) {
        unsigned pr = p[i];
        int dl = (pr >> 16) & 255;
        int pos = bbase + lscan[dl] + atomicAdd(&hist[dl], 1);
        col[pos] = (unsigned short)(pr & 0xffffu);
    }
}

// ---------------- prepW: W1 -> fragment-packed RNE bf16 ----------------

__global__ __launch_bounds__(256) void prepW_kernel(const float* __restrict__ W1,
        short* __restrict__ Wp) {
    const int g = blockIdx.x * 256 + threadIdx.x;  // 0..8191
    const int f = g >> 6;
    const int lane = g & 63;
    const int ks = f >> 3, nt = f & 7;
    const int colg = nt * 16 + (lane & 15);
    const int k0 = ks * 32 + (lane >> 4) * 8;
    short8 vb;
    #pragma unroll
    for (int j = 0; j < 8; ++j) {
        unsigned u = f2u(W1[(size_t)(k0 + j) * NHID + colg]);
        unsigned r = (u + 0x7fffu + ((u >> 16) & 1u)) >> 16;   // RNE
        vb[j] = (short)r;
    }
    *reinterpret_cast<short8*>(Wp + ((size_t)f << 9) + (lane << 3)) = vb;
}

// ---------------- GEMM1: m97-style global_load_lds + MFMA, BM=64 (R16) ----------------

__device__ __forceinline__ void cvt8v(const f32x4& u0, const f32x4& u1,
                                      short8& h, short8& l) {
    float av[8] = {u0[0], u0[1], u0[2], u0[3], u1[0], u1[1], u1[2], u1[3]};
    #pragma unroll
    for (int j = 0; j < 8; ++j) {
        unsigned u = f2u(av[j]);
        h[j] = (short)(u >> 16);
        float hif = u2f(u & 0xffff0000u);
        l[j] = (short)(f2u(av[j] - hif) >> 16);
    }
}

#define STAGE(bufidx, ksv) do { \
    const char* _xb = (const char*)X + (size_t)(ksv) * 128; \
    char* _ab = (char*)&Abuf[bufidx][0] + tid * 16; \
    __builtin_amdgcn_global_load_lds((const unsigned*)(_xb + aoff0), (unsigned*)(_ab),        16, 0, 0); \
    __builtin_amdgcn_global_load_lds((const unsigned*)(_xb + aoff1), (unsigned*)(_ab + 4096), 16, 0, 0); \
    const char* _wb = (const char*)Wp + (size_t)(ksv) * 8192 + tid * 16; \
    char* _bb = (char*)&Bbuf[bufidx][0] + tid * 16; \
    __builtin_amdgcn_global_load_lds((const unsigned*)(_wb),        (unsigned*)(_bb),        16, 0, 0); \
    __builtin_amdgcn_global_load_lds((const unsigned*)(_wb + 4096), (unsigned*)(_bb + 4096), 16, 0, 0); \
} while (0)

__global__ __launch_bounds__(256, 4) void gemm1_mfma(
        const float* __restrict__ X, const short* __restrict__ Wp,
        const float* __restrict__ dinv, __half* __restrict__ Hs16, int M) {
    __shared__ float Abuf[2][BM * BK];   // 8KB each
    __shared__ short Bbuf[2][8 * 512];   // 8KB each
    const int tid = threadIdx.x;
    const int lane = tid & 63;
    const int wid = tid >> 6;
    const int l15 = lane & 15;
    const int kc = lane >> 4;
    const int m0 = blockIdx.x * BM;

    int aoff0, aoff1;
    {
        int o, row, c, grow;
        o = tid * 16;        row = o >> 7; c = ((o >> 4) & 7) ^ (row & 7);
        grow = m0 + row; if (grow > M - 1) grow = M - 1; aoff0 = grow * 2048 + c * 16;
        o = 4096 + tid * 16; row = o >> 7; c = ((o >> 4) & 7) ^ (row & 7);
        grow = m0 + row; if (grow > M - 1) grow = M - 1; aoff1 = grow * 2048 + c * 16;
    }

    const int row0 = wid * 16 + l15;
    const int ra0 = row0 * 128 + (((kc * 2) ^ (row0 & 7)) * 16);
    const int ra1 = row0 * 128 + (((kc * 2 + 1) ^ (row0 & 7)) * 16);

    f32x4 acc[8];
    #pragma unroll
    for (int j = 0; j < 8; ++j)
        acc[j] = (f32x4){0.f, 0.f, 0.f, 0.f};

    STAGE(0, 0);
    __syncthreads();

    for (int ks = 0; ks < 16; ++ks) {
        const int cur = ks & 1;
        if (ks + 1 < 16) STAGE(cur ^ 1, ks + 1);
        const char* ab = (const char*)&Abuf[cur][0];
        const f32x4 x0 = *reinterpret_cast<const f32x4*>(ab + ra0);
        const f32x4 x1 = *reinterpret_cast<const f32x4*>(ab + ra1);
        short8 ah, al;
        cvt8v(x0, x1, ah, al);
        const char* bb = (const char*)&Bbuf[cur][0];
        short8 bfr[8];
        #pragma unroll
        for (int nt = 0; nt < 8; ++nt)
            bfr[nt] = *reinterpret_cast<const short8*>(bb + nt * 1024 + lane * 16);
        #pragma unroll
        for (int nt = 0; nt < 8; ++nt) {
            acc[nt] = __builtin_amdgcn_mfma_f32_16x16x32_bf16(ah, bfr[nt], acc[nt], 0, 0, 0);
            acc[nt] = __builtin_amdgcn_mfma_f32_16x16x32_bf16(al, bfr[nt], acc[nt], 0, 0, 0);
        }
        __syncthreads();
    }

    #pragma unroll
    for (int r = 0; r < 4; ++r) {
        const int orow = m0 + wid * 16 + kc * 4 + r;
        if (orow < M) {
            const float di = dinv[orow];
            #pragma unroll
            for (int nt = 0; nt < 8; ++nt) {
                Hs16[(size_t)orow * NHID + nt * 16 + l15] =
                    __float2half(acc[nt][r] * di);
            }
        }
    }
}

// ---------------- AGG1: 1 node/block; Y16 = fp16(relu(dinv*(self+sum)+b1)) ----------------

__global__ __launch_bounds__(64) void agg1_kernel(const __half2* __restrict__ Hs,
        const int* __restrict__ row_ptr, const unsigned short* __restrict__ col,
        const float* __restrict__ dinv, const float* __restrict__ b1,
        __half2* __restrict__ Y16) {
    const int i = blockIdx.x;
    const int c = threadIdx.x;           // col-pair 0..63
    const int beg = row_ptr[i], end = row_ptr[i + 1];
    float2 f = __half22float2(Hs[(size_t)i * 64 + c]);
    float ax = f.x, ay = f.y;
    int e = beg;
    for (; e + 8 <= end; e += 8) {
        float2 v[8];
        #pragma unroll
        for (int j = 0; j < 8; ++j) {
            int s = col[e + j];
            v[j] = __half22float2(Hs[(size_t)s * 64 + c]);
        }
        #pragma unroll
        for (int j = 0; j < 8; ++j) { ax += v[j].x; ay += v[j].y; }
    }
    for (; e < end; ++e) {
        float2 v = __half22float2(Hs[(size_t)col[e] * 64 + c]);
        ax += v.x; ay += v.y;
    }
    const float di = dinv[i];
    const float2 bb = reinterpret_cast<const float2*>(b1)[c];
    float ox = fmaxf(fmaf(ax, di, bb.x), 0.0f);
    float oy = fmaxf(fmaf(ay, di, bb.y), 0.0f);
    Y16[(size_t)i * 64 + c] = __floats2half2_rn(ox, oy);
}

// ---------------- GEMM2: H2s16 = fp16((Y16 @ W2) * dinv[row])  [N,64] ----------------

__global__ __launch_bounds__(256) void gemm2_kernel(const __half2* __restrict__ Y16,
        const float* __restrict__ W2, const float* __restrict__ dinv,
        __half* __restrict__ H2s16, int N) {
    __shared__ float Ws[NHID][NCLS];     // 32KB
    __shared__ __half2 Ys2[16][NCLS];    // 4KB
    const int tid = threadIdx.x;
    const int i0 = blockIdx.x * 16;
    #pragma unroll
    for (int t = 0; t < 8; ++t) {
        int v = tid + t * 256;
        int k = v >> 4;
        int c4 = (v & 15) * 4;
        *reinterpret_cast<float4*>(&Ws[k][c4]) =
            *reinterpret_cast<const float4*>(&W2[(size_t)k * NCLS + c4]);
    }
    {
        int r = tid >> 4;
        int c4 = (tid & 15) * 4;
        int gr = i0 + r; if (gr > N - 1) gr = N - 1;
        *reinterpret_cast<float4*>(&Ys2[r][c4]) =
            *reinterpret_cast<const float4*>(&Y16[(size_t)gr * 64 + c4]);
    }
    __syncthreads();
    const int c = tid & 63;
    const int rg = tid >> 6;
    float acc[4] = {0.f, 0.f, 0.f, 0.f};
    #pragma unroll 8
    for (int kp = 0; kp < 64; ++kp) {
        const float w0 = Ws[2 * kp][c];
        const float w1 = Ws[2 * kp + 1][c];
        #pragma unroll
        for (int j = 0; j < 4; ++j) {
            float2 y2 = __half22float2(Ys2[rg * 4 + j][kp]);
            acc[j] = fmaf(y2.x, w0, fmaf(y2.y, w1, acc[j]));
        }
    }
    #pragma unroll
    for (int j = 0; j < 4; ++j) {
        int gr = i0 + rg * 4 + j;
        if (gr < N) H2s16[(size_t)gr * NCLS + c] = __float2half(acc[j] * dinv[gr]);
    }
}

// ---------------- AGG2 + softmax: two nodes per wave ----------------

__global__ __launch_bounds__(64) void agg2_kernel(const __half2* __restrict__ H2,
        const int* __restrict__ row_ptr, const unsigned short* __restrict__ col,
        const float* __restrict__ dinv, const float* __restrict__ b2,
        float* __restrict__ out, int N) {
    const int lane = threadIdx.x;
    const int node = blockIdx.x * 2 + (lane >> 5);
    const int c = lane & 31;             // col-pair 0..31
    if (node >= N) return;
    const int beg = row_ptr[node], end = row_ptr[node + 1];
    float2 f = __half22float2(H2[(size_t)node * 32 + c]);
    float ax = f.x, ay = f.y;
    int e = beg;
    for (; e + 8 <= end; e += 8) {
        float2 v[8];
        #pragma unroll
        for (int j = 0; j < 8; ++j) {
            int s = col[e + j];
            v[j] = __half22float2(H2[(size_t)s * 32 + c]);
        }
        #pragma unroll
        for (int j = 0; j < 8; ++j) { ax += v[j].x; ay += v[j].y; }
    }
    for (; e < end; ++e) {
        float2 v = __half22float2(H2[(size_t)col[e] * 32 + c]);
        ax += v.x; ay += v.y;
    }
    const float di = dinv[node];
    const float2 bb = reinterpret_cast<const float2*>(b2)[c];
    float vx = fmaf(ax, di, bb.x);
    float vy = fmaf(ay, di, bb.y);
    float m = fmaxf(vx, vy);
    #pragma unroll
    for (int d = 16; d >= 1; d >>= 1) m = fmaxf(m, __shfl_xor(m, d));
    float ex = __expf(vx - m), ey = __expf(vy - m);
    float sum = ex + ey;
    #pragma unroll
    for (int d = 16; d >= 1; d >>= 1) sum += __shfl_xor(sum, d);
    float2 o = {ex / sum, ey / sum};
    reinterpret_cast<float2*>(out)[(size_t)node * 32 + c] = o;
}

// ---------------- launch ----------------

extern "C" void kernel_launch(void* const* d_in, const int* in_sizes, int n_in,
                              void* d_out, int out_size, void* d_ws, size_t ws_size,
                              hipStream_t stream) {
    const float* x  = (const float*)d_in[0];
    const int*   ei = (const int*)d_in[1];
    const float* W1 = (const float*)d_in[2];
    const float* b1 = (const float*)d_in[3];
    const float* W2 = (const float*)d_in[4];
    const float* b2 = (const float*)d_in[5];
    const int N = in_sizes[0] / F_IN;
    const int E = in_sizes[1] / 2;
    const int* src = ei;
    const int* dst = ei + E;
    float* out = (float*)d_out;

    const int Npad  = (N + 63) & ~63;             // >= N+1
    const int Epad  = (E + 63) & ~63;
    const int nbuck = (N + 255) >> BSHIFT;                  // 196
    const int cap = (((E / nbuck) * 3 / 2) + 63) & ~63;     // ~12288

    int*            bcur    = (int*)d_ws;                           // 256
    int*            row_ptr = bcur + 256;                           // Npad
    float*          dinv    = (float*)(row_ptr + Npad);             // Npad
    unsigned short* col     = (unsigned short*)(dinv + Npad);       // Epad u16 (3.2MB)
    __half*         Hs16    = (__half*)(col + Epad);                // Npad*128 (12.8MB)
    __half2*        Y16     = (__half2*)(Hs16 + (size_t)Npad * NHID); // Npad*64 half2
    short*          Wp      = (short*)(Y16 + (size_t)Npad * 64);    // 65536 shorts
    unsigned*       pairs   = (unsigned*)(Wp + 65536);              // nbuck*cap u32
    __half*         H2s16   = Hs16;                                 // reuse

    hipMemsetAsync(bcur, 0, 256 * sizeof(int), stream);
    bin_kernel<<<(E + CHUNK - 1) / CHUNK, 256, 0, stream>>>(src, dst, pairs, bcur, E, cap);
    countfill_b_kernel<<<nbuck, 1024, 0, stream>>>(pairs, bcur, row_ptr, dinv, col, cap, N);
    prepW_kernel<<<32, 256, 0, stream>>>(W1, Wp);
    gemm1_mfma<<<(N + BM - 1) / BM, 256, 0, stream>>>(x, Wp, dinv, Hs16, N);
    agg1_kernel<<<N, 64, 0, stream>>>((const __half2*)Hs16, row_ptr, col, dinv, b1, Y16);
    gemm2_kernel<<<(N + 15) / 16, 256, 0, stream>>>(Y16, W2, dinv, H2s16, N);
    agg2_kernel<<<(N + 1) / 2, 64, 0, stream>>>((const __half2*)H2s16, row_ptr, col, dinv, b2, out, N);
}

// Round 20
// 169.599 us; speedup vs baseline: 1.1079x; 1.0090x over previous
//
#include <hip/hip_runtime.h>
#include <hip/hip_bf16.h>
#include <hip/hip_fp16.h>

// ---------------------------------------------------------------------------
// GCN 2-layer inference:
//   h1 = relu( D^-1/2 (A+I) D^-1/2 (x @ W1) + b1 )
//   out = softmax( D^-1/2 (A+I) D^-1/2 (h1 @ W2) + b2 )
//
// memset(bcur) -> bin (packed u32 pairs, LDS counting-sort) -> countfill_b
// (fused hist+prefix+row_ptr/dinv+CSR place) -> prepW -> gemm1_mfma
// (m97-style global_load_lds, 2-buffer, 4 blocks/CU) -> agg1_fused
// (fp16 gather + Y in LDS + layer-2 linear, W2 L1-resident) -> agg2
// (+softmax).
//
// Round-19 lesson: ushort col was neutral/negative (u16 scalar loads offset
// the byte saving) -> col back to int. This round: gemm2 fused into agg1 --
// Y never leaves LDS (kills 25.6MB round trip + one dispatch; W2 is exactly
// 32KB = L1 size so the added reads are L1-hits, not L2/L3 lines).
// ---------------------------------------------------------------------------

#define F_IN 512
#define NHID 128
#define NCLS 64
#define BSHIFT 8           // 256 nodes per bucket
#define CHUNK 4096         // edges per bin block
#define BM 64
#define BK 32

typedef __attribute__((ext_vector_type(8))) short short8;
typedef __attribute__((ext_vector_type(4))) float f32x4;

__device__ __forceinline__ unsigned f2u(float f) { union { float f; unsigned u; } v; v.f = f; return v.u; }
__device__ __forceinline__ float u2f(unsigned u) { union { unsigned u; float f; } v; v.u = u; return v.f; }

// ---------------- binning: LDS counting-sort, packed u32 pairs ----------------

__global__ __launch_bounds__(256) void bin_kernel(const int* __restrict__ src,
        const int* __restrict__ dst, unsigned* __restrict__ pairs,
        int* __restrict__ bcur, int E, int cap) {
    __shared__ int lcnt[256];
    __shared__ int lscan[256];
    __shared__ int gbase[256];
    __shared__ int wsum[4];
    __shared__ unsigned stage[CHUNK];   // 16KB
    const int t = threadIdx.x;
    const int lane = t & 63, wid = t >> 6;
    const int e0 = blockIdx.x * CHUNK;
    const int n = min(CHUNK, E - e0);

    lcnt[t] = 0;
    __syncthreads();
    for (int i = t; i < n; i += 256)
        atomicAdd(&lcnt[dst[e0 + i] >> BSHIFT], 1);
    __syncthreads();
    const int v = lcnt[t];
    int s = v;
    #pragma unroll
    for (int d = 1; d < 64; d <<= 1) {
        int tt = __shfl_up(s, d);
        if (lane >= d) s += tt;
    }
    if (lane == 63) wsum[wid] = s;
    __syncthreads();
    int woff = 0;
    for (int w = 0; w < wid; ++w) woff += wsum[w];
    lscan[t] = woff + s - v;
    gbase[t] = v ? atomicAdd(&bcur[t], v) : 0;
    lcnt[t] = 0;
    __syncthreads();
    for (int i = t; i < n; i += 256) {
        unsigned d = (unsigned)dst[e0 + i], sc = (unsigned)src[e0 + i];
        int b = d >> BSHIFT;
        int p = atomicAdd(&lcnt[b], 1);
        stage[lscan[b] + p] = (d << 16) | sc;
    }
    __syncthreads();
    for (int i = t; i < n; i += 256) {
        unsigned pr = stage[i];
        int b = pr >> 24;
        int off = gbase[b] + (i - lscan[b]);
        if (off < cap) pairs[(size_t)b * cap + off] = pr;
    }
}

// ---------------- fused: per-bucket hist + prefix -> row_ptr/dinv + CSR place ----------------

__global__ __launch_bounds__(1024) void countfill_b_kernel(
        const unsigned* __restrict__ pairs, const int* __restrict__ bcur,
        int* __restrict__ row_ptr, float* __restrict__ dinv,
        int* __restrict__ col, int cap, int N) {
    __shared__ int hist[256];
    __shared__ int lscan[256];
    __shared__ int red[16];
    __shared__ int wsum[4];
    const int b = blockIdx.x;
    const int t = threadIdx.x;
    const int lane = t & 63, wv = t >> 6;

    int bv = (t < 256 && t < b) ? min(bcur[t], cap) : 0;
    #pragma unroll
    for (int d = 32; d >= 1; d >>= 1) bv += __shfl_xor(bv, d);
    if (lane == 0) red[wv] = bv;
    if (t < 256) hist[t] = 0;
    __syncthreads();
    int bbase = 0;
    #pragma unroll
    for (int w = 0; w < 16; ++w) bbase += red[w];

    const int n = min(bcur[b], cap);
    const unsigned* p = pairs + (size_t)b * cap;
    for (int i = t; i < n; i += 1024)
        atomicAdd(&hist[(p[i] >> 16) & 255], 1);
    __syncthreads();

    int s = 0, v2 = 0;
    if (t < 256) {
        v2 = hist[t];
        s = v2;
        #pragma unroll
        for (int d = 1; d < 64; d <<= 1) {
            int tt = __shfl_up(s, d);
            if (lane >= d) s += tt;
        }
        if (lane == 63) wsum[wv] = s;
    }
    __syncthreads();
    if (t < 256) {
        int woff = 0;
        for (int w = 0; w < wv; ++w) woff += wsum[w];
        const int excl = woff + s - v2;
        lscan[t] = excl;
        const int node = (b << BSHIFT) + t;
        if (node <= N) row_ptr[node] = bbase + excl;
        if (node < N) dinv[node] = rsqrtf((float)v2 + 1.0f);
    }
    __syncthreads();
    if (t < 256) hist[t] = 0;   // reuse as cursor
    __syncthreads();
    for (int i = t; i < n; i += 1024) {
        unsigned pr = p[i];
        int dl = (pr >> 16) & 255;
        int pos = bbase + lscan[dl] + atomicAdd(&hist[dl], 1);
        col[pos] = (int)(pr & 0xffffu);
    }
}

// ---------------- prepW: W1 -> fragment-packed RNE bf16 ----------------

__global__ __launch_bounds__(256) void prepW_kernel(const float* __restrict__ W1,
        short* __restrict__ Wp) {
    const int g = blockIdx.x * 256 + threadIdx.x;  // 0..8191
    const int f = g >> 6;
    const int lane = g & 63;
    const int ks = f >> 3, nt = f & 7;
    const int colg = nt * 16 + (lane & 15);
    const int k0 = ks * 32 + (lane >> 4) * 8;
    short8 vb;
    #pragma unroll
    for (int j = 0; j < 8; ++j) {
        unsigned u = f2u(W1[(size_t)(k0 + j) * NHID + colg]);
        unsigned r = (u + 0x7fffu + ((u >> 16) & 1u)) >> 16;   // RNE
        vb[j] = (short)r;
    }
    *reinterpret_cast<short8*>(Wp + ((size_t)f << 9) + (lane << 3)) = vb;
}

// ---------------- GEMM1: m97-style global_load_lds + MFMA, BM=64 (R16) ----------------

__device__ __forceinline__ void cvt8v(const f32x4& u0, const f32x4& u1,
                                      short8& h, short8& l) {
    float av[8] = {u0[0], u0[1], u0[2], u0[3], u1[0], u1[1], u1[2], u1[3]};
    #pragma unroll
    for (int j = 0; j < 8; ++j) {
        unsigned u = f2u(av[j]);
        h[j] = (short)(u >> 16);
        float hif = u2f(u & 0xffff0000u);
        l[j] = (short)(f2u(av[j] - hif) >> 16);
    }
}

#define STAGE(bufidx, ksv) do { \
    const char* _xb = (const char*)X + (size_t)(ksv) * 128; \
    char* _ab = (char*)&Abuf[bufidx][0] + tid * 16; \
    __builtin_amdgcn_global_load_lds((const unsigned*)(_xb + aoff0), (unsigned*)(_ab),        16, 0, 0); \
    __builtin_amdgcn_global_load_lds((const unsigned*)(_xb + aoff1), (unsigned*)(_ab + 4096), 16, 0, 0); \
    const char* _wb = (const char*)Wp + (size_t)(ksv) * 8192 + tid * 16; \
    char* _bb = (char*)&Bbuf[bufidx][0] + tid * 16; \
    __builtin_amdgcn_global_load_lds((const unsigned*)(_wb),        (unsigned*)(_bb),        16, 0, 0); \
    __builtin_amdgcn_global_load_lds((const unsigned*)(_wb + 4096), (unsigned*)(_bb + 4096), 16, 0, 0); \
} while (0)

__global__ __launch_bounds__(256, 4) void gemm1_mfma(
        const float* __restrict__ X, const short* __restrict__ Wp,
        const float* __restrict__ dinv, __half* __restrict__ Hs16, int M) {
    __shared__ float Abuf[2][BM * BK];   // 8KB each
    __shared__ short Bbuf[2][8 * 512];   // 8KB each
    const int tid = threadIdx.x;
    const int lane = tid & 63;
    const int wid = tid >> 6;
    const int l15 = lane & 15;
    const int kc = lane >> 4;
    const int m0 = blockIdx.x * BM;

    int aoff0, aoff1;
    {
        int o, row, c, grow;
        o = tid * 16;        row = o >> 7; c = ((o >> 4) & 7) ^ (row & 7);
        grow = m0 + row; if (grow > M - 1) grow = M - 1; aoff0 = grow * 2048 + c * 16;
        o = 4096 + tid * 16; row = o >> 7; c = ((o >> 4) & 7) ^ (row & 7);
        grow = m0 + row; if (grow > M - 1) grow = M - 1; aoff1 = grow * 2048 + c * 16;
    }

    const int row0 = wid * 16 + l15;
    const int ra0 = row0 * 128 + (((kc * 2) ^ (row0 & 7)) * 16);
    const int ra1 = row0 * 128 + (((kc * 2 + 1) ^ (row0 & 7)) * 16);

    f32x4 acc[8];
    #pragma unroll
    for (int j = 0; j < 8; ++j)
        acc[j] = (f32x4){0.f, 0.f, 0.f, 0.f};

    STAGE(0, 0);
    __syncthreads();

    for (int ks = 0; ks < 16; ++ks) {
        const int cur = ks & 1;
        if (ks + 1 < 16) STAGE(cur ^ 1, ks + 1);
        const char* ab = (const char*)&Abuf[cur][0];
        const f32x4 x0 = *reinterpret_cast<const f32x4*>(ab + ra0);
        const f32x4 x1 = *reinterpret_cast<const f32x4*>(ab + ra1);
        short8 ah, al;
        cvt8v(x0, x1, ah, al);
        const char* bb = (const char*)&Bbuf[cur][0];
        short8 bfr[8];
        #pragma unroll
        for (int nt = 0; nt < 8; ++nt)
            bfr[nt] = *reinterpret_cast<const short8*>(bb + nt * 1024 + lane * 16);
        #pragma unroll
        for (int nt = 0; nt < 8; ++nt) {
            acc[nt] = __builtin_amdgcn_mfma_f32_16x16x32_bf16(ah, bfr[nt], acc[nt], 0, 0, 0);
            acc[nt] = __builtin_amdgcn_mfma_f32_16x16x32_bf16(al, bfr[nt], acc[nt], 0, 0, 0);
        }
        __syncthreads();
    }

    #pragma unroll
    for (int r = 0; r < 4; ++r) {
        const int orow = m0 + wid * 16 + kc * 4 + r;
        if (orow < M) {
            const float di = dinv[orow];
            #pragma unroll
            for (int nt = 0; nt < 8; ++nt) {
                Hs16[(size_t)orow * NHID + nt * 16 + l15] =
                    __float2half(acc[nt][r] * di);
            }
        }
    }
}

// ---------------- AGG1+GEMM2 fused: 1 node/block ----------------
// Phase 1 (gather): ax,ay = self + sum Hs[src]; y = relu(dinv*axy + b1),
// parked in LDS (fp32, 512B). Phase 2 (linear): H2[i][c] = dinv_i *
// sum_k y[k]*W2[k][c]; W2 reads are 256B coalesced per k and L1-resident
// (32KB = L1 size), so no extra L2/L3 line traffic.

__global__ __launch_bounds__(64) void agg1_fused_kernel(const __half2* __restrict__ Hs,
        const int* __restrict__ row_ptr, const int* __restrict__ col,
        const float* __restrict__ dinv, const float* __restrict__ b1,
        const float* __restrict__ W2, __half* __restrict__ H2) {
    __shared__ float Ylds[128];
    const int i = blockIdx.x;
    const int c = threadIdx.x;           // col-pair 0..63
    const int beg = row_ptr[i], end = row_ptr[i + 1];
    float2 f = __half22float2(Hs[(size_t)i * 64 + c]);
    float ax = f.x, ay = f.y;
    int e = beg;
    for (; e + 8 <= end; e += 8) {
        float2 v[8];
        #pragma unroll
        for (int j = 0; j < 8; ++j) {
            int s = col[e + j];
            v[j] = __half22float2(Hs[(size_t)s * 64 + c]);
        }
        #pragma unroll
        for (int j = 0; j < 8; ++j) { ax += v[j].x; ay += v[j].y; }
    }
    for (; e < end; ++e) {
        float2 v = __half22float2(Hs[(size_t)col[e] * 64 + c]);
        ax += v.x; ay += v.y;
    }
    const float di = dinv[i];
    const float2 bb = reinterpret_cast<const float2*>(b1)[c];
    Ylds[2 * c]     = fmaxf(fmaf(ax, di, bb.x), 0.0f);
    Ylds[2 * c + 1] = fmaxf(fmaf(ay, di, bb.y), 0.0f);
    __syncthreads();
    float acc0 = 0.f, acc1 = 0.f, acc2 = 0.f, acc3 = 0.f;
    #pragma unroll 4
    for (int k = 0; k < 128; k += 4) {
        acc0 = fmaf(Ylds[k + 0], W2[(k + 0) * NCLS + c], acc0);
        acc1 = fmaf(Ylds[k + 1], W2[(k + 1) * NCLS + c], acc1);
        acc2 = fmaf(Ylds[k + 2], W2[(k + 2) * NCLS + c], acc2);
        acc3 = fmaf(Ylds[k + 3], W2[(k + 3) * NCLS + c], acc3);
    }
    H2[(size_t)i * NCLS + c] = __float2half(((acc0 + acc1) + (acc2 + acc3)) * di);
}

// ---------------- AGG2 + softmax: two nodes per wave ----------------

__global__ __launch_bounds__(64) void agg2_kernel(const __half2* __restrict__ H2,
        const int* __restrict__ row_ptr, const int* __restrict__ col,
        const float* __restrict__ dinv, const float* __restrict__ b2,
        float* __restrict__ out, int N) {
    const int lane = threadIdx.x;
    const int node = blockIdx.x * 2 + (lane >> 5);
    const int c = lane & 31;             // col-pair 0..31
    if (node >= N) return;
    const int beg = row_ptr[node], end = row_ptr[node + 1];
    float2 f = __half22float2(H2[(size_t)node * 32 + c]);
    float ax = f.x, ay = f.y;
    int e = beg;
    for (; e + 8 <= end; e += 8) {
        float2 v[8];
        #pragma unroll
        for (int j = 0; j < 8; ++j) {
            int s = col[e + j];
            v[j] = __half22float2(H2[(size_t)s * 32 + c]);
        }
        #pragma unroll
        for (int j = 0; j < 8; ++j) { ax += v[j].x; ay += v[j].y; }
    }
    for (; e < end; ++e) {
        float2 v = __half22float2(H2[(size_t)col[e] * 32 + c]);
        ax += v.x; ay += v.y;
    }
    const float di = dinv[node];
    const float2 bb = reinterpret_cast<const float2*>(b2)[c];
    float vx = fmaf(ax, di, bb.x);
    float vy = fmaf(ay, di, bb.y);
    float m = fmaxf(vx, vy);
    #pragma unroll
    for (int d = 16; d >= 1; d >>= 1) m = fmaxf(m, __shfl_xor(m, d));
    float ex = __expf(vx - m), ey = __expf(vy - m);
    float sum = ex + ey;
    #pragma unroll
    for (int d = 16; d >= 1; d >>= 1) sum += __shfl_xor(sum, d);
    float2 o = {ex / sum, ey / sum};
    reinterpret_cast<float2*>(out)[(size_t)node * 32 + c] = o;
}

// ---------------- launch ----------------

extern "C" void kernel_launch(void* const* d_in, const int* in_sizes, int n_in,
                              void* d_out, int out_size, void* d_ws, size_t ws_size,
                              hipStream_t stream) {
    const float* x  = (const float*)d_in[0];
    const int*   ei = (const int*)d_in[1];
    const float* W1 = (const float*)d_in[2];
    const float* b1 = (const float*)d_in[3];
    const float* W2 = (const float*)d_in[4];
    const float* b2 = (const float*)d_in[5];
    const int N = in_sizes[0] / F_IN;
    const int E = in_sizes[1] / 2;
    const int* src = ei;
    const int* dst = ei + E;
    float* out = (float*)d_out;

    const int Npad  = (N + 63) & ~63;             // >= N+1
    const int Epad  = (E + 63) & ~63;
    const int nbuck = (N + 255) >> BSHIFT;                  // 196
    const int cap = (((E / nbuck) * 3 / 2) + 63) & ~63;     // ~12288

    int*      bcur    = (int*)d_ws;                           // 256
    int*      row_ptr = bcur + 256;                           // Npad
    float*    dinv    = (float*)(row_ptr + Npad);             // Npad
    int*      col     = (int*)(dinv + Npad);                  // Epad (6.4MB)
    __half*   Hs16    = (__half*)(col + Epad);                // Npad*128 (12.8MB)
    __half*   H2s16   = Hs16 + (size_t)Npad * NHID;           // Npad*64 (6.4MB)
    short*    Wp      = (short*)(H2s16 + (size_t)Npad * NCLS); // 65536 shorts
    unsigned* pairs   = (unsigned*)(Wp + 65536);              // nbuck*cap u32

    hipMemsetAsync(bcur, 0, 256 * sizeof(int), stream);
    bin_kernel<<<(E + CHUNK - 1) / CHUNK, 256, 0, stream>>>(src, dst, pairs, bcur, E, cap);
    countfill_b_kernel<<<nbuck, 1024, 0, stream>>>(pairs, bcur, row_ptr, dinv, col, cap, N);
    prepW_kernel<<<32, 256, 0, stream>>>(W1, Wp);
    gemm1_mfma<<<(N + BM - 1) / BM, 256, 0, stream>>>(x, Wp, dinv, Hs16, N);
    agg1_fused_kernel<<<N, 64, 0, stream>>>((const __half2*)Hs16, row_ptr, col, dinv, b1, W2, H2s16);
    agg2_kernel<<<(N + 1) / 2, 64, 0, stream>>>((const __half2*)H2s16, row_ptr, col, dinv, b2, out, N);
}

// Round 21
// 155.339 us; speedup vs baseline: 1.2096x; 1.0918x over previous
//
#include <hip/hip_runtime.h>
#include <hip/hip_bf16.h>
#include <hip/hip_fp16.h>

// ---------------------------------------------------------------------------
// GCN 2-layer inference:
//   h1 = relu( D^-1/2 (A+I) D^-1/2 (x @ W1) + b1 )
//   out = softmax( D^-1/2 (A+I) D^-1/2 (h1 @ W2) + b2 )
//
// memset(bcur) -> bin (packed u32 pairs, LDS counting-sort) -> countfill_b
// (fused hist+prefix+row_ptr/dinv+CSR place) -> prepW (W1 bf16 frag-pack)
// -> prepW2 (W2 fp16 k-pair pack, 16KB L1-resident) -> gemm1_mfma
// (m97-style global_load_lds, 2-buffer, 4 blocks/CU) -> agg1_fused
// (fp16 gather + Y in LDS + layer-2 linear with half2 W2: 64 loads not 128)
// -> agg2 (+softmax).
//
// Round-20 lesson: fusion was net-neutral -- phase-2's 128 serialized L1
// loads ate the saved Y round-trip. half2 W2 pairs halve phase-2 loads.
// ---------------------------------------------------------------------------

#define F_IN 512
#define NHID 128
#define NCLS 64
#define BSHIFT 8           // 256 nodes per bucket
#define CHUNK 4096         // edges per bin block
#define BM 64
#define BK 32

typedef __attribute__((ext_vector_type(8))) short short8;
typedef __attribute__((ext_vector_type(4))) float f32x4;

__device__ __forceinline__ unsigned f2u(float f) { union { float f; unsigned u; } v; v.f = f; return v.u; }
__device__ __forceinline__ float u2f(unsigned u) { union { unsigned u; float f; } v; v.u = u; return v.f; }

// ---------------- binning: LDS counting-sort, packed u32 pairs ----------------

__global__ __launch_bounds__(256) void bin_kernel(const int* __restrict__ src,
        const int* __restrict__ dst, unsigned* __restrict__ pairs,
        int* __restrict__ bcur, int E, int cap) {
    __shared__ int lcnt[256];
    __shared__ int lscan[256];
    __shared__ int gbase[256];
    __shared__ int wsum[4];
    __shared__ unsigned stage[CHUNK];   // 16KB
    const int t = threadIdx.x;
    const int lane = t & 63, wid = t >> 6;
    const int e0 = blockIdx.x * CHUNK;
    const int n = min(CHUNK, E - e0);

    lcnt[t] = 0;
    __syncthreads();
    for (int i = t; i < n; i += 256)
        atomicAdd(&lcnt[dst[e0 + i] >> BSHIFT], 1);
    __syncthreads();
    const int v = lcnt[t];
    int s = v;
    #pragma unroll
    for (int d = 1; d < 64; d <<= 1) {
        int tt = __shfl_up(s, d);
        if (lane >= d) s += tt;
    }
    if (lane == 63) wsum[wid] = s;
    __syncthreads();
    int woff = 0;
    for (int w = 0; w < wid; ++w) woff += wsum[w];
    lscan[t] = woff + s - v;
    gbase[t] = v ? atomicAdd(&bcur[t], v) : 0;
    lcnt[t] = 0;
    __syncthreads();
    for (int i = t; i < n; i += 256) {
        unsigned d = (unsigned)dst[e0 + i], sc = (unsigned)src[e0 + i];
        int b = d >> BSHIFT;
        int p = atomicAdd(&lcnt[b], 1);
        stage[lscan[b] + p] = (d << 16) | sc;
    }
    __syncthreads();
    for (int i = t; i < n; i += 256) {
        unsigned pr = stage[i];
        int b = pr >> 24;
        int off = gbase[b] + (i - lscan[b]);
        if (off < cap) pairs[(size_t)b * cap + off] = pr;
    }
}

// ---------------- fused: per-bucket hist + prefix -> row_ptr/dinv + CSR place ----------------

__global__ __launch_bounds__(1024) void countfill_b_kernel(
        const unsigned* __restrict__ pairs, const int* __restrict__ bcur,
        int* __restrict__ row_ptr, float* __restrict__ dinv,
        int* __restrict__ col, int cap, int N) {
    __shared__ int hist[256];
    __shared__ int lscan[256];
    __shared__ int red[16];
    __shared__ int wsum[4];
    const int b = blockIdx.x;
    const int t = threadIdx.x;
    const int lane = t & 63, wv = t >> 6;

    int bv = (t < 256 && t < b) ? min(bcur[t], cap) : 0;
    #pragma unroll
    for (int d = 32; d >= 1; d >>= 1) bv += __shfl_xor(bv, d);
    if (lane == 0) red[wv] = bv;
    if (t < 256) hist[t] = 0;
    __syncthreads();
    int bbase = 0;
    #pragma unroll
    for (int w = 0; w < 16; ++w) bbase += red[w];

    const int n = min(bcur[b], cap);
    const unsigned* p = pairs + (size_t)b * cap;
    for (int i = t; i < n; i += 1024)
        atomicAdd(&hist[(p[i] >> 16) & 255], 1);
    __syncthreads();

    int s = 0, v2 = 0;
    if (t < 256) {
        v2 = hist[t];
        s = v2;
        #pragma unroll
        for (int d = 1; d < 64; d <<= 1) {
            int tt = __shfl_up(s, d);
            if (lane >= d) s += tt;
        }
        if (lane == 63) wsum[wv] = s;
    }
    __syncthreads();
    if (t < 256) {
        int woff = 0;
        for (int w = 0; w < wv; ++w) woff += wsum[w];
        const int excl = woff + s - v2;
        lscan[t] = excl;
        const int node = (b << BSHIFT) + t;
        if (node <= N) row_ptr[node] = bbase + excl;
        if (node < N) dinv[node] = rsqrtf((float)v2 + 1.0f);
    }
    __syncthreads();
    if (t < 256) hist[t] = 0;   // reuse as cursor
    __syncthreads();
    for (int i = t; i < n; i += 1024) {
        unsigned pr = p[i];
        int dl = (pr >> 16) & 255;
        int pos = bbase + lscan[dl] + atomicAdd(&hist[dl], 1);
        col[pos] = (int)(pr & 0xffffu);
    }
}

// ---------------- prepW: W1 -> fragment-packed RNE bf16 ----------------

__global__ __launch_bounds__(256) void prepW_kernel(const float* __restrict__ W1,
        short* __restrict__ Wp) {
    const int g = blockIdx.x * 256 + threadIdx.x;  // 0..8191
    const int f = g >> 6;
    const int lane = g & 63;
    const int ks = f >> 3, nt = f & 7;
    const int colg = nt * 16 + (lane & 15);
    const int k0 = ks * 32 + (lane >> 4) * 8;
    short8 vb;
    #pragma unroll
    for (int j = 0; j < 8; ++j) {
        unsigned u = f2u(W1[(size_t)(k0 + j) * NHID + colg]);
        unsigned r = (u + 0x7fffu + ((u >> 16) & 1u)) >> 16;   // RNE
        vb[j] = (short)r;
    }
    *reinterpret_cast<short8*>(Wp + ((size_t)f << 9) + (lane << 3)) = vb;
}

// ---------------- prepW2: W2 [128][64] f32 -> k-pair-packed half2 [64][64] ----------------

__global__ __launch_bounds__(256) void prepW2_kernel(const float* __restrict__ W2,
        __half2* __restrict__ Wp2) {
    const int idx = blockIdx.x * 256 + threadIdx.x;   // 0..4095
    const int kp = idx >> 6;
    const int c = idx & 63;
    Wp2[idx] = __floats2half2_rn(W2[(2 * kp) * NCLS + c], W2[(2 * kp + 1) * NCLS + c]);
}

// ---------------- GEMM1: m97-style global_load_lds + MFMA, BM=64 (R16) ----------------

__device__ __forceinline__ void cvt8v(const f32x4& u0, const f32x4& u1,
                                      short8& h, short8& l) {
    float av[8] = {u0[0], u0[1], u0[2], u0[3], u1[0], u1[1], u1[2], u1[3]};
    #pragma unroll
    for (int j = 0; j < 8; ++j) {
        unsigned u = f2u(av[j]);
        h[j] = (short)(u >> 16);
        float hif = u2f(u & 0xffff0000u);
        l[j] = (short)(f2u(av[j] - hif) >> 16);
    }
}

#define STAGE(bufidx, ksv) do { \
    const char* _xb = (const char*)X + (size_t)(ksv) * 128; \
    char* _ab = (char*)&Abuf[bufidx][0] + tid * 16; \
    __builtin_amdgcn_global_load_lds((const unsigned*)(_xb + aoff0), (unsigned*)(_ab),        16, 0, 0); \
    __builtin_amdgcn_global_load_lds((const unsigned*)(_xb + aoff1), (unsigned*)(_ab + 4096), 16, 0, 0); \
    const char* _wb = (const char*)Wp + (size_t)(ksv) * 8192 + tid * 16; \
    char* _bb = (char*)&Bbuf[bufidx][0] + tid * 16; \
    __builtin_amdgcn_global_load_lds((const unsigned*)(_wb),        (unsigned*)(_bb),        16, 0, 0); \
    __builtin_amdgcn_global_load_lds((const unsigned*)(_wb + 4096), (unsigned*)(_bb + 4096), 16, 0, 0); \
} while (0)

__global__ __launch_bounds__(256, 4) void gemm1_mfma(
        const float* __restrict__ X, const short* __restrict__ Wp,
        const float* __restrict__ dinv, __half* __restrict__ Hs16, int M) {
    __shared__ float Abuf[2][BM * BK];   // 8KB each
    __shared__ short Bbuf[2][8 * 512];   // 8KB each
    const int tid = threadIdx.x;
    const int lane = tid & 63;
    const int wid = tid >> 6;
    const int l15 = lane & 15;
    const int kc = lane >> 4;
    const int m0 = blockIdx.x * BM;

    int aoff0, aoff1;
    {
        int o, row, c, grow;
        o = tid * 16;        row = o >> 7; c = ((o >> 4) & 7) ^ (row & 7);
        grow = m0 + row; if (grow > M - 1) grow = M - 1; aoff0 = grow * 2048 + c * 16;
        o = 4096 + tid * 16; row = o >> 7; c = ((o >> 4) & 7) ^ (row & 7);
        grow = m0 + row; if (grow > M - 1) grow = M - 1; aoff1 = grow * 2048 + c * 16;
    }

    const int row0 = wid * 16 + l15;
    const int ra0 = row0 * 128 + (((kc * 2) ^ (row0 & 7)) * 16);
    const int ra1 = row0 * 128 + (((kc * 2 + 1) ^ (row0 & 7)) * 16);

    f32x4 acc[8];
    #pragma unroll
    for (int j = 0; j < 8; ++j)
        acc[j] = (f32x4){0.f, 0.f, 0.f, 0.f};

    STAGE(0, 0);
    __syncthreads();

    for (int ks = 0; ks < 16; ++ks) {
        const int cur = ks & 1;
        if (ks + 1 < 16) STAGE(cur ^ 1, ks + 1);
        const char* ab = (const char*)&Abuf[cur][0];
        const f32x4 x0 = *reinterpret_cast<const f32x4*>(ab + ra0);
        const f32x4 x1 = *reinterpret_cast<const f32x4*>(ab + ra1);
        short8 ah, al;
        cvt8v(x0, x1, ah, al);
        const char* bb = (const char*)&Bbuf[cur][0];
        short8 bfr[8];
        #pragma unroll
        for (int nt = 0; nt < 8; ++nt)
            bfr[nt] = *reinterpret_cast<const short8*>(bb + nt * 1024 + lane * 16);
        #pragma unroll
        for (int nt = 0; nt < 8; ++nt) {
            acc[nt] = __builtin_amdgcn_mfma_f32_16x16x32_bf16(ah, bfr[nt], acc[nt], 0, 0, 0);
            acc[nt] = __builtin_amdgcn_mfma_f32_16x16x32_bf16(al, bfr[nt], acc[nt], 0, 0, 0);
        }
        __syncthreads();
    }

    #pragma unroll
    for (int r = 0; r < 4; ++r) {
        const int orow = m0 + wid * 16 + kc * 4 + r;
        if (orow < M) {
            const float di = dinv[orow];
            #pragma unroll
            for (int nt = 0; nt < 8; ++nt) {
                Hs16[(size_t)orow * NHID + nt * 16 + l15] =
                    __float2half(acc[nt][r] * di);
            }
        }
    }
}

// ---------------- AGG1+GEMM2 fused: 1 node/block, half2 W2 ----------------

__global__ __launch_bounds__(64) void agg1_fused_kernel(const __half2* __restrict__ Hs,
        const int* __restrict__ row_ptr, const int* __restrict__ col,
        const float* __restrict__ dinv, const float* __restrict__ b1,
        const __half2* __restrict__ Wp2, __half* __restrict__ H2) {
    __shared__ float Ylds[128];
    const int i = blockIdx.x;
    const int c = threadIdx.x;           // col-pair 0..63
    const int beg = row_ptr[i], end = row_ptr[i + 1];
    float2 f = __half22float2(Hs[(size_t)i * 64 + c]);
    float ax = f.x, ay = f.y;
    int e = beg;
    for (; e + 8 <= end; e += 8) {
        float2 v[8];
        #pragma unroll
        for (int j = 0; j < 8; ++j) {
            int s = col[e + j];
            v[j] = __half22float2(Hs[(size_t)s * 64 + c]);
        }
        #pragma unroll
        for (int j = 0; j < 8; ++j) { ax += v[j].x; ay += v[j].y; }
    }
    for (; e < end; ++e) {
        float2 v = __half22float2(Hs[(size_t)col[e] * 64 + c]);
        ax += v.x; ay += v.y;
    }
    const float di = dinv[i];
    const float2 bb = reinterpret_cast<const float2*>(b1)[c];
    Ylds[2 * c]     = fmaxf(fmaf(ax, di, bb.x), 0.0f);
    Ylds[2 * c + 1] = fmaxf(fmaf(ay, di, bb.y), 0.0f);
    __syncthreads();
    float acc0 = 0.f, acc1 = 0.f;
    #pragma unroll 8
    for (int kp = 0; kp < 64; kp += 2) {
        float2 w0 = __half22float2(Wp2[kp * 64 + c]);
        float2 w1 = __half22float2(Wp2[(kp + 1) * 64 + c]);
        acc0 = fmaf(Ylds[2 * kp + 0], w0.x, fmaf(Ylds[2 * kp + 1], w0.y, acc0));
        acc1 = fmaf(Ylds[2 * kp + 2], w1.x, fmaf(Ylds[2 * kp + 3], w1.y, acc1));
    }
    H2[(size_t)i * NCLS + c] = __float2half((acc0 + acc1) * di);
}

// ---------------- AGG2 + softmax: two nodes per wave ----------------

__global__ __launch_bounds__(64) void agg2_kernel(const __half2* __restrict__ H2,
        const int* __restrict__ row_ptr, const int* __restrict__ col,
        const float* __restrict__ dinv, const float* __restrict__ b2,
        float* __restrict__ out, int N) {
    const int lane = threadIdx.x;
    const int node = blockIdx.x * 2 + (lane >> 5);
    const int c = lane & 31;             // col-pair 0..31
    if (node >= N) return;
    const int beg = row_ptr[node], end = row_ptr[node + 1];
    float2 f = __half22float2(H2[(size_t)node * 32 + c]);
    float ax = f.x, ay = f.y;
    int e = beg;
    for (; e + 8 <= end; e += 8) {
        float2 v[8];
        #pragma unroll
        for (int j = 0; j < 8; ++j) {
            int s = col[e + j];
            v[j] = __half22float2(H2[(size_t)s * 32 + c]);
        }
        #pragma unroll
        for (int j = 0; j < 8; ++j) { ax += v[j].x; ay += v[j].y; }
    }
    for (; e < end; ++e) {
        float2 v = __half22float2(H2[(size_t)col[e] * 32 + c]);
        ax += v.x; ay += v.y;
    }
    const float di = dinv[node];
    const float2 bb = reinterpret_cast<const float2*>(b2)[c];
    float vx = fmaf(ax, di, bb.x);
    float vy = fmaf(ay, di, bb.y);
    float m = fmaxf(vx, vy);
    #pragma unroll
    for (int d = 16; d >= 1; d >>= 1) m = fmaxf(m, __shfl_xor(m, d));
    float ex = __expf(vx - m), ey = __expf(vy - m);
    float sum = ex + ey;
    #pragma unroll
    for (int d = 16; d >= 1; d >>= 1) sum += __shfl_xor(sum, d);
    float2 o = {ex / sum, ey / sum};
    reinterpret_cast<float2*>(out)[(size_t)node * 32 + c] = o;
}

// ---------------- launch ----------------

extern "C" void kernel_launch(void* const* d_in, const int* in_sizes, int n_in,
                              void* d_out, int out_size, void* d_ws, size_t ws_size,
                              hipStream_t stream) {
    const float* x  = (const float*)d_in[0];
    const int*   ei = (const int*)d_in[1];
    const float* W1 = (const float*)d_in[2];
    const float* b1 = (const float*)d_in[3];
    const float* W2 = (const float*)d_in[4];
    const float* b2 = (const float*)d_in[5];
    const int N = in_sizes[0] / F_IN;
    const int E = in_sizes[1] / 2;
    const int* src = ei;
    const int* dst = ei + E;
    float* out = (float*)d_out;

    const int Npad  = (N + 63) & ~63;             // >= N+1
    const int Epad  = (E + 63) & ~63;
    const int nbuck = (N + 255) >> BSHIFT;                  // 196
    const int cap = (((E / nbuck) * 3 / 2) + 63) & ~63;     // ~12288

    int*      bcur    = (int*)d_ws;                           // 256
    int*      row_ptr = bcur + 256;                           // Npad
    float*    dinv    = (float*)(row_ptr + Npad);             // Npad
    int*      col     = (int*)(dinv + Npad);                  // Epad (6.4MB)
    __half*   Hs16    = (__half*)(col + Epad);                // Npad*128 (12.8MB)
    __half*   H2s16   = Hs16 + (size_t)Npad * NHID;           // Npad*64 (6.4MB)
    short*    Wp      = (short*)(H2s16 + (size_t)Npad * NCLS); // 65536 shorts
    __half2*  Wp2     = (__half2*)(Wp + 65536);               // 4096 half2 (16KB)
    unsigned* pairs   = (unsigned*)(Wp2 + 4096);              // nbuck*cap u32

    hipMemsetAsync(bcur, 0, 256 * sizeof(int), stream);
    bin_kernel<<<(E + CHUNK - 1) / CHUNK, 256, 0, stream>>>(src, dst, pairs, bcur, E, cap);
    countfill_b_kernel<<<nbuck, 1024, 0, stream>>>(pairs, bcur, row_ptr, dinv, col, cap, N);
    prepW_kernel<<<32, 256, 0, stream>>>(W1, Wp);
    prepW2_kernel<<<16, 256, 0, stream>>>(W2, Wp2);
    gemm1_mfma<<<(N + BM - 1) / BM, 256, 0, stream>>>(x, Wp, dinv, Hs16, N);
    agg1_fused_kernel<<<N, 64, 0, stream>>>((const __half2*)Hs16, row_ptr, col, dinv, b1, Wp2, H2s16);
    agg2_kernel<<<(N + 1) / 2, 64, 0, stream>>>((const __half2*)H2s16, row_ptr, col, dinv, b2, out, N);
}

// Round 22
// 151.300 us; speedup vs baseline: 1.2419x; 1.0267x over previous
//
#include <hip/hip_runtime.h>
#include <hip/hip_bf16.h>
#include <hip/hip_fp16.h>

// ---------------------------------------------------------------------------
// GCN 2-layer inference:
//   h1 = relu( D^-1/2 (A+I) D^-1/2 (x @ W1) + b1 )
//   out = softmax( D^-1/2 (A+I) D^-1/2 (h1 @ W2) + b2 )
//
// memset(bcur) -> bin (packed u32 pairs, LDS counting-sort) -> countfill_b
// (fused hist+prefix+row_ptr/dinv+CSR place) -> prepW (W1 bf16 frag-pack)
// -> prepW2 (W2 fp16 k-pair pack, 16KB L1-resident) -> gemm1_mfma
// (m97-style global_load_lds, 2-buffer, 4 blocks/CU) -> agg1_fused
// (fp16 gather + Y half2 in LDS + layer-2 linear via v_dot2_f32_f16)
// -> agg2 (+softmax).
//
// Round-21 lesson: agg1_fused is VALU-co-limited (57.7% busy). fdot2 cuts
// phase-2 to {1 LDS broadcast + 1 L1 load + 1 dot} per k-pair; fp16 Y was
// already accuracy-verified in R16-R19.
// ---------------------------------------------------------------------------

#define F_IN 512
#define NHID 128
#define NCLS 64
#define BSHIFT 8           // 256 nodes per bucket
#define CHUNK 4096         // edges per bin block
#define BM 64
#define BK 32

typedef __attribute__((ext_vector_type(8))) short short8;
typedef __attribute__((ext_vector_type(4))) float f32x4;
typedef __attribute__((ext_vector_type(2))) _Float16 h2v;

__device__ __forceinline__ unsigned f2u(float f) { union { float f; unsigned u; } v; v.f = f; return v.u; }
__device__ __forceinline__ float u2f(unsigned u) { union { unsigned u; float f; } v; v.u = u; return v.f; }
__device__ __forceinline__ h2v h2cast(__half2 x) { union { __half2 a; h2v b; } u; u.a = x; return u.b; }

// ---------------- binning: LDS counting-sort, packed u32 pairs ----------------

__global__ __launch_bounds__(256) void bin_kernel(const int* __restrict__ src,
        const int* __restrict__ dst, unsigned* __restrict__ pairs,
        int* __restrict__ bcur, int E, int cap) {
    __shared__ int lcnt[256];
    __shared__ int lscan[256];
    __shared__ int gbase[256];
    __shared__ int wsum[4];
    __shared__ unsigned stage[CHUNK];   // 16KB
    const int t = threadIdx.x;
    const int lane = t & 63, wid = t >> 6;
    const int e0 = blockIdx.x * CHUNK;
    const int n = min(CHUNK, E - e0);

    lcnt[t] = 0;
    __syncthreads();
    for (int i = t; i < n; i += 256)
        atomicAdd(&lcnt[dst[e0 + i] >> BSHIFT], 1);
    __syncthreads();
    const int v = lcnt[t];
    int s = v;
    #pragma unroll
    for (int d = 1; d < 64; d <<= 1) {
        int tt = __shfl_up(s, d);
        if (lane >= d) s += tt;
    }
    if (lane == 63) wsum[wid] = s;
    __syncthreads();
    int woff = 0;
    for (int w = 0; w < wid; ++w) woff += wsum[w];
    lscan[t] = woff + s - v;
    gbase[t] = v ? atomicAdd(&bcur[t], v) : 0;
    lcnt[t] = 0;
    __syncthreads();
    for (int i = t; i < n; i += 256) {
        unsigned d = (unsigned)dst[e0 + i], sc = (unsigned)src[e0 + i];
        int b = d >> BSHIFT;
        int p = atomicAdd(&lcnt[b], 1);
        stage[lscan[b] + p] = (d << 16) | sc;
    }
    __syncthreads();
    for (int i = t; i < n; i += 256) {
        unsigned pr = stage[i];
        int b = pr >> 24;
        int off = gbase[b] + (i - lscan[b]);
        if (off < cap) pairs[(size_t)b * cap + off] = pr;
    }
}

// ---------------- fused: per-bucket hist + prefix -> row_ptr/dinv + CSR place ----------------

__global__ __launch_bounds__(1024) void countfill_b_kernel(
        const unsigned* __restrict__ pairs, const int* __restrict__ bcur,
        int* __restrict__ row_ptr, float* __restrict__ dinv,
        int* __restrict__ col, int cap, int N) {
    __shared__ int hist[256];
    __shared__ int lscan[256];
    __shared__ int red[16];
    __shared__ int wsum[4];
    const int b = blockIdx.x;
    const int t = threadIdx.x;
    const int lane = t & 63, wv = t >> 6;

    int bv = (t < 256 && t < b) ? min(bcur[t], cap) : 0;
    #pragma unroll
    for (int d = 32; d >= 1; d >>= 1) bv += __shfl_xor(bv, d);
    if (lane == 0) red[wv] = bv;
    if (t < 256) hist[t] = 0;
    __syncthreads();
    int bbase = 0;
    #pragma unroll
    for (int w = 0; w < 16; ++w) bbase += red[w];

    const int n = min(bcur[b], cap);
    const unsigned* p = pairs + (size_t)b * cap;
    for (int i = t; i < n; i += 1024)
        atomicAdd(&hist[(p[i] >> 16) & 255], 1);
    __syncthreads();

    int s = 0, v2 = 0;
    if (t < 256) {
        v2 = hist[t];
        s = v2;
        #pragma unroll
        for (int d = 1; d < 64; d <<= 1) {
            int tt = __shfl_up(s, d);
            if (lane >= d) s += tt;
        }
        if (lane == 63) wsum[wv] = s;
    }
    __syncthreads();
    if (t < 256) {
        int woff = 0;
        for (int w = 0; w < wv; ++w) woff += wsum[w];
        const int excl = woff + s - v2;
        lscan[t] = excl;
        const int node = (b << BSHIFT) + t;
        if (node <= N) row_ptr[node] = bbase + excl;
        if (node < N) dinv[node] = rsqrtf((float)v2 + 1.0f);
    }
    __syncthreads();
    if (t < 256) hist[t] = 0;   // reuse as cursor
    __syncthreads();
    for (int i = t; i < n; i += 1024) {
        unsigned pr = p[i];
        int dl = (pr >> 16) & 255;
        int pos = bbase + lscan[dl] + atomicAdd(&hist[dl], 1);
        col[pos] = (int)(pr & 0xffffu);
    }
}

// ---------------- prepW: W1 -> fragment-packed RNE bf16 ----------------

__global__ __launch_bounds__(256) void prepW_kernel(const float* __restrict__ W1,
        short* __restrict__ Wp) {
    const int g = blockIdx.x * 256 + threadIdx.x;  // 0..8191
    const int f = g >> 6;
    const int lane = g & 63;
    const int ks = f >> 3, nt = f & 7;
    const int colg = nt * 16 + (lane & 15);
    const int k0 = ks * 32 + (lane >> 4) * 8;
    short8 vb;
    #pragma unroll
    for (int j = 0; j < 8; ++j) {
        unsigned u = f2u(W1[(size_t)(k0 + j) * NHID + colg]);
        unsigned r = (u + 0x7fffu + ((u >> 16) & 1u)) >> 16;   // RNE
        vb[j] = (short)r;
    }
    *reinterpret_cast<short8*>(Wp + ((size_t)f << 9) + (lane << 3)) = vb;
}

// ---------------- prepW2: W2 [128][64] f32 -> k-pair-packed half2 [64][64] ----------------

__global__ __launch_bounds__(256) void prepW2_kernel(const float* __restrict__ W2,
        __half2* __restrict__ Wp2) {
    const int idx = blockIdx.x * 256 + threadIdx.x;   // 0..4095
    const int kp = idx >> 6;
    const int c = idx & 63;
    Wp2[idx] = __floats2half2_rn(W2[(2 * kp) * NCLS + c], W2[(2 * kp + 1) * NCLS + c]);
}

// ---------------- GEMM1: m97-style global_load_lds + MFMA, BM=64 (R16) ----------------

__device__ __forceinline__ void cvt8v(const f32x4& u0, const f32x4& u1,
                                      short8& h, short8& l) {
    float av[8] = {u0[0], u0[1], u0[2], u0[3], u1[0], u1[1], u1[2], u1[3]};
    #pragma unroll
    for (int j = 0; j < 8; ++j) {
        unsigned u = f2u(av[j]);
        h[j] = (short)(u >> 16);
        float hif = u2f(u & 0xffff0000u);
        l[j] = (short)(f2u(av[j] - hif) >> 16);
    }
}

#define STAGE(bufidx, ksv) do { \
    const char* _xb = (const char*)X + (size_t)(ksv) * 128; \
    char* _ab = (char*)&Abuf[bufidx][0] + tid * 16; \
    __builtin_amdgcn_global_load_lds((const unsigned*)(_xb + aoff0), (unsigned*)(_ab),        16, 0, 0); \
    __builtin_amdgcn_global_load_lds((const unsigned*)(_xb + aoff1), (unsigned*)(_ab + 4096), 16, 0, 0); \
    const char* _wb = (const char*)Wp + (size_t)(ksv) * 8192 + tid * 16; \
    char* _bb = (char*)&Bbuf[bufidx][0] + tid * 16; \
    __builtin_amdgcn_global_load_lds((const unsigned*)(_wb),        (unsigned*)(_bb),        16, 0, 0); \
    __builtin_amdgcn_global_load_lds((const unsigned*)(_wb + 4096), (unsigned*)(_bb + 4096), 16, 0, 0); \
} while (0)

__global__ __launch_bounds__(256, 4) void gemm1_mfma(
        const float* __restrict__ X, const short* __restrict__ Wp,
        const float* __restrict__ dinv, __half* __restrict__ Hs16, int M) {
    __shared__ float Abuf[2][BM * BK];   // 8KB each
    __shared__ short Bbuf[2][8 * 512];   // 8KB each
    const int tid = threadIdx.x;
    const int lane = tid & 63;
    const int wid = tid >> 6;
    const int l15 = lane & 15;
    const int kc = lane >> 4;
    const int m0 = blockIdx.x * BM;

    int aoff0, aoff1;
    {
        int o, row, c, grow;
        o = tid * 16;        row = o >> 7; c = ((o >> 4) & 7) ^ (row & 7);
        grow = m0 + row; if (grow > M - 1) grow = M - 1; aoff0 = grow * 2048 + c * 16;
        o = 4096 + tid * 16; row = o >> 7; c = ((o >> 4) & 7) ^ (row & 7);
        grow = m0 + row; if (grow > M - 1) grow = M - 1; aoff1 = grow * 2048 + c * 16;
    }

    const int row0 = wid * 16 + l15;
    const int ra0 = row0 * 128 + (((kc * 2) ^ (row0 & 7)) * 16);
    const int ra1 = row0 * 128 + (((kc * 2 + 1) ^ (row0 & 7)) * 16);

    f32x4 acc[8];
    #pragma unroll
    for (int j = 0; j < 8; ++j)
        acc[j] = (f32x4){0.f, 0.f, 0.f, 0.f};

    STAGE(0, 0);
    __syncthreads();

    for (int ks = 0; ks < 16; ++ks) {
        const int cur = ks & 1;
        if (ks + 1 < 16) STAGE(cur ^ 1, ks + 1);
        const char* ab = (const char*)&Abuf[cur][0];
        const f32x4 x0 = *reinterpret_cast<const f32x4*>(ab + ra0);
        const f32x4 x1 = *reinterpret_cast<const f32x4*>(ab + ra1);
        short8 ah, al;
        cvt8v(x0, x1, ah, al);
        const char* bb = (const char*)&Bbuf[cur][0];
        short8 bfr[8];
        #pragma unroll
        for (int nt = 0; nt < 8; ++nt)
            bfr[nt] = *reinterpret_cast<const short8*>(bb + nt * 1024 + lane * 16);
        #pragma unroll
        for (int nt = 0; nt < 8; ++nt) {
            acc[nt] = __builtin_amdgcn_mfma_f32_16x16x32_bf16(ah, bfr[nt], acc[nt], 0, 0, 0);
            acc[nt] = __builtin_amdgcn_mfma_f32_16x16x32_bf16(al, bfr[nt], acc[nt], 0, 0, 0);
        }
        __syncthreads();
    }

    #pragma unroll
    for (int r = 0; r < 4; ++r) {
        const int orow = m0 + wid * 16 + kc * 4 + r;
        if (orow < M) {
            const float di = dinv[orow];
            #pragma unroll
            for (int nt = 0; nt < 8; ++nt) {
                Hs16[(size_t)orow * NHID + nt * 16 + l15] =
                    __float2half(acc[nt][r] * di);
            }
        }
    }
}

// ---------------- AGG1+GEMM2 fused: 1 node/block, fdot2 phase-2 ----------------

__global__ __launch_bounds__(64) void agg1_fused_kernel(const __half2* __restrict__ Hs,
        const int* __restrict__ row_ptr, const int* __restrict__ col,
        const float* __restrict__ dinv, const float* __restrict__ b1,
        const __half2* __restrict__ Wp2, __half* __restrict__ H2) {
    __shared__ __half2 Ylds[64];
    const int i = blockIdx.x;
    const int c = threadIdx.x;           // col-pair 0..63
    const int beg = row_ptr[i], end = row_ptr[i + 1];
    float2 f = __half22float2(Hs[(size_t)i * 64 + c]);
    float ax = f.x, ay = f.y;
    int e = beg;
    for (; e + 8 <= end; e += 8) {
        float2 v[8];
        #pragma unroll
        for (int j = 0; j < 8; ++j) {
            int s = col[e + j];
            v[j] = __half22float2(Hs[(size_t)s * 64 + c]);
        }
        #pragma unroll
        for (int j = 0; j < 8; ++j) { ax += v[j].x; ay += v[j].y; }
    }
    for (; e < end; ++e) {
        float2 v = __half22float2(Hs[(size_t)col[e] * 64 + c]);
        ax += v.x; ay += v.y;
    }
    const float di = dinv[i];
    const float2 bb = reinterpret_cast<const float2*>(b1)[c];
    float ox = fmaxf(fmaf(ax, di, bb.x), 0.0f);
    float oy = fmaxf(fmaf(ay, di, bb.y), 0.0f);
    Ylds[c] = __floats2half2_rn(ox, oy);
    __syncthreads();                     // single-wave block: cheap
    float acc0 = 0.f, acc1 = 0.f;
    #pragma unroll 8
    for (int kp = 0; kp < 64; kp += 2) {
        acc0 = __builtin_amdgcn_fdot2(h2cast(Ylds[kp]),     h2cast(Wp2[kp * 64 + c]),       acc0, false);
        acc1 = __builtin_amdgcn_fdot2(h2cast(Ylds[kp + 1]), h2cast(Wp2[(kp + 1) * 64 + c]), acc1, false);
    }
    H2[(size_t)i * NCLS + c] = __float2half((acc0 + acc1) * di);
}

// ---------------- AGG2 + softmax: two nodes per wave ----------------

__global__ __launch_bounds__(64) void agg2_kernel(const __half2* __restrict__ H2,
        const int* __restrict__ row_ptr, const int* __restrict__ col,
        const float* __restrict__ dinv, const float* __restrict__ b2,
        float* __restrict__ out, int N) {
    const int lane = threadIdx.x;
    const int node = blockIdx.x * 2 + (lane >> 5);
    const int c = lane & 31;             // col-pair 0..31
    if (node >= N) return;
    const int beg = row_ptr[node], end = row_ptr[node + 1];
    float2 f = __half22float2(H2[(size_t)node * 32 + c]);
    float ax = f.x, ay = f.y;
    int e = beg;
    for (; e + 8 <= end; e += 8) {
        float2 v[8];
        #pragma unroll
        for (int j = 0; j < 8; ++j) {
            int s = col[e + j];
            v[j] = __half22float2(H2[(size_t)s * 32 + c]);
        }
        #pragma unroll
        for (int j = 0; j < 8; ++j) { ax += v[j].x; ay += v[j].y; }
    }
    for (; e < end; ++e) {
        float2 v = __half22float2(H2[(size_t)col[e] * 32 + c]);
        ax += v.x; ay += v.y;
    }
    const float di = dinv[node];
    const float2 bb = reinterpret_cast<const float2*>(b2)[c];
    float vx = fmaf(ax, di, bb.x);
    float vy = fmaf(ay, di, bb.y);
    float m = fmaxf(vx, vy);
    #pragma unroll
    for (int d = 16; d >= 1; d >>= 1) m = fmaxf(m, __shfl_xor(m, d));
    float ex = __expf(vx - m), ey = __expf(vy - m);
    float sum = ex + ey;
    #pragma unroll
    for (int d = 16; d >= 1; d >>= 1) sum += __shfl_xor(sum, d);
    float2 o = {ex / sum, ey / sum};
    reinterpret_cast<float2*>(out)[(size_t)node * 32 + c] = o;
}

// ---------------- launch ----------------

extern "C" void kernel_launch(void* const* d_in, const int* in_sizes, int n_in,
                              void* d_out, int out_size, void* d_ws, size_t ws_size,
                              hipStream_t stream) {
    const float* x  = (const float*)d_in[0];
    const int*   ei = (const int*)d_in[1];
    const float* W1 = (const float*)d_in[2];
    const float* b1 = (const float*)d_in[3];
    const float* W2 = (const float*)d_in[4];
    const float* b2 = (const float*)d_in[5];
    const int N = in_sizes[0] / F_IN;
    const int E = in_sizes[1] / 2;
    const int* src = ei;
    const int* dst = ei + E;
    float* out = (float*)d_out;

    const int Npad  = (N + 63) & ~63;             // >= N+1
    const int Epad  = (E + 63) & ~63;
    const int nbuck = (N + 255) >> BSHIFT;                  // 196
    const int cap = (((E / nbuck) * 3 / 2) + 63) & ~63;     // ~12288

    int*      bcur    = (int*)d_ws;                           // 256
    int*      row_ptr = bcur + 256;                           // Npad
    float*    dinv    = (float*)(row_ptr + Npad);             // Npad
    int*      col     = (int*)(dinv + Npad);                  // Epad (6.4MB)
    __half*   Hs16    = (__half*)(col + Epad);                // Npad*128 (12.8MB)
    __half*   H2s16   = Hs16 + (size_t)Npad * NHID;           // Npad*64 (6.4MB)
    short*    Wp      = (short*)(H2s16 + (size_t)Npad * NCLS); // 65536 shorts
    __half2*  Wp2     = (__half2*)(Wp + 65536);               // 4096 half2 (16KB)
    unsigned* pairs   = (unsigned*)(Wp2 + 4096);              // nbuck*cap u32

    hipMemsetAsync(bcur, 0, 256 * sizeof(int), stream);
    bin_kernel<<<(E + CHUNK - 1) / CHUNK, 256, 0, stream>>>(src, dst, pairs, bcur, E, cap);
    countfill_b_kernel<<<nbuck, 1024, 0, stream>>>(pairs, bcur, row_ptr, dinv, col, cap, N);
    prepW_kernel<<<32, 256, 0, stream>>>(W1, Wp);
    prepW2_kernel<<<16, 256, 0, stream>>>(W2, Wp2);
    gemm1_mfma<<<(N + BM - 1) / BM, 256, 0, stream>>>(x, Wp, dinv, Hs16, N);
    agg1_fused_kernel<<<N, 64, 0, stream>>>((const __half2*)Hs16, row_ptr, col, dinv, b1, Wp2, H2s16);
    agg2_kernel<<<(N + 1) / 2, 64, 0, stream>>>((const __half2*)H2s16, row_ptr, col, dinv, b2, out, N);
}